// Round 13
// baseline (1614.620 us; speedup 1.0000x reference)
//
#include <hip/hip_runtime.h>
#include <cstddef>

#define B_   64
#define N_   512
#define NV_  32768
#define NE_  8192
#define NNZ_ 262144
#define SNNZ_ 24576
#define D_   300
#define HID_ 256
#define NC_  10
#define VOCAB_ 30000
#define PCHUNK 8
#define PVN (N_ / PCHUNK)   // 64 nodes per pool chunk

#define SCAN_TOT (NE_ + NV_ + NE_)      // 49152 counts, contiguous [cnt_e|cnt_v|cnt_s]
#define SCAN_NCH (SCAN_TOT / 1024)      // 48 chunks
#define SEG1_CH  (NE_ / 1024)           // 8  (start of cnt_v chunks)
#define SEG2_CH  ((NE_ + NV_) / 1024)   // 40 (start of cnt_s chunks)

#define CSR_BLOCKS 512
#define CH_BLOCKS  1024

using u16 = unsigned short;
typedef __attribute__((ext_vector_type(8))) short short8;
typedef __attribute__((ext_vector_type(4))) float f32x4;

__device__ __forceinline__ float bf2f(u16 v) {
    union { unsigned int u; float f; } uf;
    uf.u = ((unsigned int)v) << 16;
    return uf.f;
}
__device__ __forceinline__ u16 f2bf(float f) {
    union { float f; unsigned int u; } uf; uf.f = f;
    unsigned int u = uf.u;
    unsigned int r = u + 0x7fffu + ((u >> 16) & 1u);
    return (u16)(r >> 16);
}

// software grid barrier: all blocks co-resident. Poll with AGENT-scope atomic load
// (cache-bypassing) — a plain volatile load is served stale from the non-coherent
// per-XCD L2 and spins ~150us until eviction (round-12 regression).
__device__ __forceinline__ void gbar(int* bar, int nblk) {
    __syncthreads();
    if (threadIdx.x == 0) {
        __threadfence();   // release: writeback dirty L2 lines
        __hip_atomic_fetch_add(bar, 1, __ATOMIC_ACQ_REL, __HIP_MEMORY_SCOPE_AGENT);
        while (__hip_atomic_load(bar, __ATOMIC_ACQUIRE, __HIP_MEMORY_SCOPE_AGENT) < nblk)
            __builtin_amdgcn_s_sleep(2);
        __threadfence();   // acquire: invalidate local caches
    }
    __syncthreads();
}

// ---------------- mega CSR build + weight conversion (single launch) ----------------
// P0 wconv | P1 hist | bar | P2 scanA | bar | P3 scanB | bar | P4 scanC | bar | P5 place
__global__ __launch_bounds__(256) void csr_build_kernel(
    const int* __restrict__ inc_rows, const int* __restrict__ inc_cols,
    const float* __restrict__ inc_vals,
    const int* __restrict__ sent_rows, const int* __restrict__ sent_cols,
    const float* __restrict__ sent_vals,
    const int* __restrict__ x, const float* __restrict__ deg_e,
    const float* __restrict__ deg_v,
    const float* __restrict__ W1, const float* __restrict__ W2,
    u16* __restrict__ Wt1h, u16* __restrict__ Wt1l,
    u16* __restrict__ Wt2h, u16* __restrict__ Wt2l,
    int* __restrict__ cnt, int* __restrict__ fill,
    int* __restrict__ rowptr_e, int* __restrict__ rowptr_v, int* __restrict__ rowptr_s,
    int* __restrict__ bsum, int* __restrict__ cbase,
    int4* __restrict__ elist, int2* __restrict__ vlist, int2* __restrict__ slist,
    int* __restrict__ bar) {
    int gtid = blockIdx.x * 256 + threadIdx.x;
    const int GSZ = CSR_BLOCKS * 256;
    __shared__ int red[256];

    // P0: weight conversion (independent of CSR phases)
    for (int idx = gtid; idx < 256 * 320 + 256 * 256; idx += GSZ) {
        int id = idx;
        const float* W; u16 *Wh, *Wl; int K, KP;
        if (id < 256 * 320) { W = W1; Wh = Wt1h; Wl = Wt1l; K = D_; KP = 320; }
        else { id -= 256 * 320; W = W2; Wh = Wt2h; Wl = Wt2l; K = HID_; KP = 256; }
        int n = id & 255, k = id >> 8;
        float v = (k < K) ? W[(size_t)k * HID_ + n] : 0.f;
        u16 hi = f2bf(v);
        Wh[(size_t)n * KP + k] = hi;
        Wl[(size_t)n * KP + k] = f2bf(v - bf2f(hi));
    }
    // P1: histogram
    for (int i = gtid; i < NNZ_; i += GSZ) {
        atomicAdd(&cnt[inc_cols[i]], 1);
        atomicAdd(&cnt[NE_ + inc_rows[i]], 1);
    }
    for (int i = gtid; i < SNNZ_; i += GSZ)
        atomicAdd(&cnt[NE_ + NV_ + sent_cols[i]], 1);
    gbar(bar + 0, CSR_BLOCKS);
    // P2: per-chunk sums
    if (blockIdx.x < SCAN_NCH) {
        int t = threadIdx.x;
        int4 v4 = reinterpret_cast<const int4*>(cnt)[blockIdx.x * 256 + t];
        red[t] = v4.x + v4.y + v4.z + v4.w;
        __syncthreads();
        for (int o = 128; o > 0; o >>= 1) {
            if (t < o) red[t] += red[t + o];
            __syncthreads();
        }
        if (t == 0) bsum[blockIdx.x] = red[0];
    }
    gbar(bar + 1, CSR_BLOCKS);
    // P3: chunk-base scan with segment resets
    if (blockIdx.x == 0 && threadIdx.x == 0) {
        int run = 0;
        for (int c = 0; c < SCAN_NCH; ++c) {
            if (c == SEG1_CH || c == SEG2_CH) run = 0;
            cbase[c] = run;
            run += bsum[c];
        }
    }
    gbar(bar + 2, CSR_BLOCKS);
    // P4: in-chunk scan -> rowptr + fill
    if (blockIdx.x < SCAN_NCH) {
        int blk = blockIdx.x, t = threadIdx.x;
        int gi = blk * 1024 + t * 4;
        int4 v4 = reinterpret_cast<const int4*>(cnt)[blk * 256 + t];
        int s0 = v4.x, s1 = s0 + v4.y, s2 = s1 + v4.z, s3 = s2 + v4.w;
        red[t] = s3;
        __syncthreads();
        for (int o = 1; o < 256; o <<= 1) {
            int a = (t >= o) ? red[t - o] : 0;
            __syncthreads();
            red[t] += a;
            __syncthreads();
        }
        int excl = (t > 0 ? red[t - 1] : 0) + cbase[blk];
        int4 ee;
        ee.x = excl; ee.y = excl + s0; ee.z = excl + s1; ee.w = excl + s2;
        int* rp; int li;
        if (blk < SEG1_CH)      { rp = rowptr_e; li = gi; }
        else if (blk < SEG2_CH) { rp = rowptr_v; li = gi - NE_; }
        else                    { rp = rowptr_s; li = gi - NE_ - NV_; }
        rp[li + 0] = ee.x; rp[li + 1] = ee.y; rp[li + 2] = ee.z; rp[li + 3] = ee.w;
        reinterpret_cast<int4*>(fill)[blk * 256 + t] = ee;
        if (t == 255) {
            int tot = excl + s3;
            if (blk == SEG1_CH - 1) rowptr_e[NE_] = tot;
            if (blk == SEG2_CH - 1) rowptr_v[NV_] = tot;
            if (blk == SCAN_NCH - 1) rowptr_s[NE_] = tot;
        }
    }
    gbar(bar + 3, CSR_BLOCKS);
    // P5: packed placement (deg folded; x folded into elist.y)
    for (int i = gtid; i < NNZ_; i += GSZ) {
        int r = inc_rows[i], c = inc_cols[i];
        float v = inc_vals[i];
        int pe = atomicAdd(&fill[c], 1);
        int4 ee;
        ee.x = r; ee.y = x[r];
        ee.z = __float_as_int(v * deg_e[c]); ee.w = 0;
        elist[pe] = ee;
        int pv = atomicAdd(&fill[NE_ + r], 1);
        int2 vv;
        vv.x = c; vv.y = __float_as_int(v * deg_v[r]);
        vlist[pv] = vv;
    }
    for (int i = gtid; i < SNNZ_; i += GSZ) {
        int ps = atomicAdd(&fill[NE_ + NV_ + sent_cols[i]], 1);
        int2 ss;
        ss.x = sent_rows[i]; ss.y = __float_as_int(sent_vals[i]);
        slist[ps] = ss;
    }
}

// ---------------- per-wave 256-dim gather helper ------------------------------------
template <int MODE>
__device__ __forceinline__ float4 seg_gather(const int* __restrict__ rowptr,
                                             const void* __restrict__ listv,
                                             const u16* __restrict__ src,
                                             int seg, int lane) {
    int start = rowptr[seg], end = rowptr[seg + 1];
    float4 acc = make_float4(0.f, 0.f, 0.f, 0.f);
    for (int k = start; k < end; ++k) {
        int r; float v;
        if constexpr (MODE == 0) {
            int2 q = ((const int2*)listv)[k];
            r = q.x; v = __int_as_float(q.y);
        } else {
            int4 q = ((const int4*)listv)[k];
            r = (MODE == 1) ? q.x : q.y;
            v = __int_as_float(q.z);
        }
        ushort4 sv = *reinterpret_cast<const ushort4*>(src + (size_t)r * 256 + lane * 4);
        acc.x += v * bf2f(sv.x); acc.y += v * bf2f(sv.y);
        acc.z += v * bf2f(sv.z); acc.w += v * bf2f(sv.w);
    }
    return acc;
}
__device__ __forceinline__ void store_bf4(u16* dst, int seg, int lane, float4 o) {
    ushort4 o4;
    o4.x = f2bf(o.x); o4.y = f2bf(o.y); o4.z = f2bf(o.z); o4.w = f2bf(o.w);
    *reinterpret_cast<ushort4*>(dst + (size_t)seg * 256 + lane * 4) = o4;
}

// ---------------- fused sparse chain: e-gather | bar | s-gather | bar | v-gather ----
template <int EMODE, bool L1EPI>
__global__ __launch_bounds__(256) void chain_kernel(const int* __restrict__ rowptr_e,
                                                    const int* __restrict__ rowptr_s,
                                                    const int* __restrict__ rowptr_v,
                                                    const int4* __restrict__ elist,
                                                    const int2* __restrict__ slist,
                                                    const int2* __restrict__ vlist,
                                                    const u16* __restrict__ esrc,
                                                    u16* __restrict__ m,
                                                    u16* __restrict__ m2,
                                                    const float* __restrict__ bias,
                                                    u16* __restrict__ outh,
                                                    const float* __restrict__ attW,
                                                    const float* __restrict__ attb,
                                                    const float* __restrict__ tfidf,
                                                    float* __restrict__ e,
                                                    int* __restrict__ bar) {
    int wid = (blockIdx.x * 256 + threadIdx.x) >> 6;
    int lane = threadIdx.x & 63;
    const int NW = CH_BLOCKS * 4;
    // e-phase
    for (int seg = wid; seg < NE_; seg += NW)
        store_bf4(m, seg, lane, seg_gather<EMODE>(rowptr_e, elist, esrc, seg, lane));
    gbar(bar + 0, CH_BLOCKS);
    // s-phase
    for (int seg = wid; seg < NE_; seg += NW)
        store_bf4(m2, seg, lane, seg_gather<0>(rowptr_s, slist, m, seg, lane));
    gbar(bar + 1, CH_BLOCKS);
    // v-phase
    for (int seg = wid; seg < NV_; seg += NW) {
        float4 o = seg_gather<0>(rowptr_v, vlist, m2, seg, lane);
        if constexpr (L1EPI) {
            float4 bv = reinterpret_cast<const float4*>(bias)[lane];
            o.x = fmaxf(o.x + bv.x, 0.f); o.y = fmaxf(o.y + bv.y, 0.f);
            o.z = fmaxf(o.z + bv.z, 0.f); o.w = fmaxf(o.w + bv.w, 0.f);
        }
        store_bf4(outh, seg, lane, o);
        if constexpr (L1EPI) {
            float4 aw = reinterpret_cast<const float4*>(attW)[lane];
            float pe = o.x * aw.x + o.y * aw.y + o.z * aw.z + o.w * aw.w;
#pragma unroll
            for (int off = 32; off > 0; off >>= 1) pe += __shfl_down(pe, off);
            if (lane == 0)
                e[seg] = pe + tfidf[seg * 2] * attW[HID_] + tfidf[seg * 2 + 1] * attW[HID_ + 1]
                         + attb[0];
        }
    }
}

// ---------------- MFMA GEMM, full-N tile 64x256: C = A @ Wt^T -----------------------
template <bool SPLIT_A, bool EPI, bool ATT>
__global__ __launch_bounds__(256) void gemm_mfma_kernel(const void* __restrict__ Av,
                                                        int M, int K, int Ks,
                                                        const u16* __restrict__ Bth,
                                                        const u16* __restrict__ Btl, int bstride,
                                                        const float* __restrict__ bias,
                                                        void* __restrict__ Cv,
                                                        const float* __restrict__ attWA,
                                                        float* __restrict__ EAp,
                                                        const float* __restrict__ attW,
                                                        const float* __restrict__ attb,
                                                        const float* __restrict__ tfidf,
                                                        float* __restrict__ e) {
    __shared__ __align__(16) u16 Ah[64 * 32];
    __shared__ __align__(16) u16 Al[64 * 32];
    __shared__ __align__(16) u16 Bh[256 * 32];
    __shared__ __align__(16) u16 Bl[256 * 32];
    int tid = threadIdx.x;
    int bm0 = blockIdx.x * 64;
    int w = tid >> 6, l = tid & 63;
    int srow = tid >> 2;
    int skbp = tid & 3;
    int skbl = skbp ^ ((srow >> 1) & 3);
    int arow = bm0 + srow; if (arow >= M) arow = M - 1;
    int sdst = srow * 32 + skbp * 8;
    int frow = w * 16 + (l & 15);
    int akbp = (l >> 4) ^ ((frow >> 1) & 3);

    f32x4 acc[16] = {};
    float ea = 0.f;
    int nkt = (K + 31) / 32;
    for (int kt = 0; kt < nkt; ++kt) {
        if (kt) __syncthreads();
        int kbase = kt * 32 + skbl * 8;
        if constexpr (SPLIT_A) {
            const float* Arow = (const float*)Av + (size_t)arow * Ks;
            float av[8];
            if (kbase + 8 <= K) {
                float4 v0 = *reinterpret_cast<const float4*>(Arow + kbase);
                float4 v1 = *reinterpret_cast<const float4*>(Arow + kbase + 4);
                av[0] = v0.x; av[1] = v0.y; av[2] = v0.z; av[3] = v0.w;
                av[4] = v1.x; av[5] = v1.y; av[6] = v1.z; av[7] = v1.w;
            } else {
#pragma unroll
                for (int ee = 0; ee < 8; ++ee) {
                    int kk = kbase + ee;
                    av[ee] = (kk < K) ? Arow[kk] : 0.f;
                }
            }
            if (EAp) {
#pragma unroll
                for (int ee = 0; ee < 8; ++ee) {
                    int kk = kbase + ee;
                    ea += av[ee] * ((kk < K) ? attWA[kk] : 0.f);
                }
            }
            short8 h8, l8;
#pragma unroll
            for (int ee = 0; ee < 8; ++ee) {
                u16 hi = f2bf(av[ee]);
                h8[ee] = (short)hi;
                l8[ee] = (short)f2bf(av[ee] - bf2f(hi));
            }
            *(short8*)&Ah[sdst] = h8;
            *(short8*)&Al[sdst] = l8;
        } else {
            const u16* Arow = (const u16*)Av + (size_t)arow * Ks;
            *(short8*)&Ah[sdst] = *(const short8*)(Arow + kbase);
        }
#pragma unroll
        for (int i = 0; i < 4; ++i) {
            int br = i * 64 + srow;
            int bkl = skbp ^ ((br >> 1) & 3);
            *(short8*)&Bh[br * 32 + skbp * 8] =
                *(const short8*)(Bth + (size_t)br * bstride + kt * 32 + bkl * 8);
            *(short8*)&Bl[br * 32 + skbp * 8] =
                *(const short8*)(Btl + (size_t)br * bstride + kt * 32 + bkl * 8);
        }
        __syncthreads();
        short8 ah = *(const short8*)&Ah[frow * 32 + akbp * 8];
        short8 al;
        if constexpr (SPLIT_A) al = *(const short8*)&Al[frow * 32 + akbp * 8];
#pragma unroll
        for (int nt = 0; nt < 16; ++nt) {
            int nrow = nt * 16 + (l & 15);
            int bkbp = (l >> 4) ^ ((nrow >> 1) & 3);
            short8 tbh = *(const short8*)&Bh[nrow * 32 + bkbp * 8];
            short8 tbl = *(const short8*)&Bl[nrow * 32 + bkbp * 8];
            acc[nt] = __builtin_amdgcn_mfma_f32_16x16x32_bf16(ah, tbh, acc[nt], 0, 0, 0);
            if constexpr (SPLIT_A)
                acc[nt] = __builtin_amdgcn_mfma_f32_16x16x32_bf16(al, tbh, acc[nt], 0, 0, 0);
            acc[nt] = __builtin_amdgcn_mfma_f32_16x16x32_bf16(ah, tbl, acc[nt], 0, 0, 0);
        }
    }
    if constexpr (SPLIT_A) {
        if (EAp) {
            ea += __shfl_xor(ea, 1);
            ea += __shfl_xor(ea, 2);
            if ((tid & 3) == 0 && bm0 + srow < M) EAp[bm0 + srow] = ea;
        }
    }
#pragma unroll
    for (int r = 0; r < 4; ++r) {
        int row = bm0 + w * 16 + (l >> 4) * 4 + r;
        if (row >= M) continue;
        float er = 0.f;
#pragma unroll
        for (int nt = 0; nt < 16; ++nt) {
            int col = nt * 16 + (l & 15);
            float v = acc[nt][r];
            if constexpr (EPI) {
                v = v + bias[col];
                v = v > 0.f ? v : 0.f;
            }
            if constexpr (ATT) er += v * attW[col];
            ((u16*)Cv)[(size_t)row * 256 + col] = f2bf(v);
        }
        if constexpr (ATT) {
            er += __shfl_xor(er, 1);
            er += __shfl_xor(er, 2);
            er += __shfl_xor(er, 4);
            er += __shfl_xor(er, 8);
            if ((l & 15) == 0)
                e[row] = er + tfidf[row * 2] * attW[HID_] + tfidf[row * 2 + 1] * attW[HID_ + 1]
                         + attb[0];
        }
    }
}

// ---------------- pool partial: fused per-graph softmax + weighted-sum + max --------
template <bool L0>
__global__ __launch_bounds__(256) void pool_partial_kernel(const void* __restrict__ h, int dim,
                                                           int stride,
                                                           const int* __restrict__ x,
                                                           const float* __restrict__ EA_or_e,
                                                           const float* __restrict__ tfidf,
                                                           const float* __restrict__ attWtail,
                                                           const float* __restrict__ attb,
                                                           float* __restrict__ psum,
                                                           float* __restrict__ pmax) {
    int b = blockIdx.x, c = blockIdx.y;
    int t = threadIdx.x;
    __shared__ float sev[N_];
    __shared__ int srows[N_];
    __shared__ float red[256];
    __shared__ float wv[PVN];
    int n0 = b * N_ + t, n1 = n0 + 256;
    float ev0, ev1;
    int r0, r1;
    if constexpr (L0) {
        r0 = x[n0]; r1 = x[n1];
        float a0 = attWtail[0], a1 = attWtail[1], ab = attb[0];
        ev0 = EA_or_e[r0] + tfidf[n0 * 2] * a0 + tfidf[n0 * 2 + 1] * a1 + ab;
        ev1 = EA_or_e[r1] + tfidf[n1 * 2] * a0 + tfidf[n1 * 2 + 1] * a1 + ab;
    } else {
        r0 = n0; r1 = n1;
        ev0 = EA_or_e[n0]; ev1 = EA_or_e[n1];
    }
    sev[t] = ev0; sev[t + 256] = ev1;
    srows[t] = r0; srows[t + 256] = r1;
    red[t] = fmaxf(ev0, ev1);
    __syncthreads();
    for (int s = 128; s > 0; s >>= 1) {
        if (t < s) red[t] = fmaxf(red[t], red[t + s]);
        __syncthreads();
    }
    float mx = red[0];
    __syncthreads();
    red[t] = expf(ev0 - mx) + expf(ev1 - mx);
    __syncthreads();
    for (int s = 128; s > 0; s >>= 1) {
        if (t < s) red[t] += red[t + s];
        __syncthreads();
    }
    float inv = 1.f / (red[0] + 1e-10f);
    if (t < PVN) wv[t] = expf(sev[c * PVN + t] - mx) * inv;
    __syncthreads();
    float s0 = 0.f, s1 = 0.f, m0 = -3.4e38f, m1 = -3.4e38f;
    int d0 = t, d1 = t + 256;
    bool has1 = d1 < dim;
    for (int i = 0; i < PVN; ++i) {
        int row = srows[c * PVN + i];
        float ww = wv[i];
        float x0, x1 = 0.f;
        if constexpr (L0) {
            const float* hp = (const float*)h + (size_t)row * stride;
            x0 = hp[d0];
            if (has1) x1 = hp[d1];
        } else {
            const u16* hp = (const u16*)h + (size_t)row * stride;
            x0 = bf2f(hp[d0]);
            if (has1) x1 = bf2f(hp[d1]);
        }
        s0 += ww * x0;
        m0 = fmaxf(m0, x0);
        if (has1) {
            s1 += ww * x1;
            m1 = fmaxf(m1, x1);
        }
    }
    size_t base = ((size_t)b * PCHUNK + c) * dim;
    psum[base + d0] = s0;
    pmax[base + d0] = m0;
    if (has1) {
        psum[base + d1] = s1;
        pmax[base + d1] = m1;
    }
}

// ---------------- final: combine chunk partials on the fly + GEMV -------------------
__global__ __launch_bounds__(256) void final_kernel(const float* __restrict__ ps0,
                                                    const float* __restrict__ pm0,
                                                    const float* __restrict__ ps1,
                                                    const float* __restrict__ pm1,
                                                    const float* __restrict__ ps2,
                                                    const float* __restrict__ pm2,
                                                    const float* __restrict__ pW0,
                                                    const float* __restrict__ pb0,
                                                    const float* __restrict__ pW1,
                                                    const float* __restrict__ pb1,
                                                    const float* __restrict__ pW2,
                                                    const float* __restrict__ pb2,
                                                    float* __restrict__ out) {
    int b = blockIdx.x;
    int t = threadIdx.x;
    int lane = t & 63, wv = t >> 6;
    float acc[NC_] = {};
    for (int k = t; k < 2 * D_; k += 256) {
        float pv;
        if (k < D_) {
            pv = 0.f;
#pragma unroll
            for (int c = 0; c < PCHUNK; ++c) pv += ps0[((size_t)b * PCHUNK + c) * D_ + k];
        } else {
            pv = -3.4e38f;
#pragma unroll
            for (int c = 0; c < PCHUNK; ++c)
                pv = fmaxf(pv, pm0[((size_t)b * PCHUNK + c) * D_ + (k - D_)]);
        }
        const float* wp = pW0 + (size_t)k * NC_;
#pragma unroll
        for (int c = 0; c < NC_; ++c) acc[c] += pv * wp[c];
    }
    for (int k = t; k < 2 * HID_; k += 256) {
        float pv;
        if (k < HID_) {
            pv = 0.f;
#pragma unroll
            for (int c = 0; c < PCHUNK; ++c) pv += ps1[((size_t)b * PCHUNK + c) * HID_ + k];
        } else {
            pv = -3.4e38f;
#pragma unroll
            for (int c = 0; c < PCHUNK; ++c)
                pv = fmaxf(pv, pm1[((size_t)b * PCHUNK + c) * HID_ + (k - HID_)]);
        }
        const float* wp = pW1 + (size_t)k * NC_;
#pragma unroll
        for (int c = 0; c < NC_; ++c) acc[c] += pv * wp[c];
    }
    for (int k = t; k < 2 * HID_; k += 256) {
        float pv;
        if (k < HID_) {
            pv = 0.f;
#pragma unroll
            for (int c = 0; c < PCHUNK; ++c) pv += ps2[((size_t)b * PCHUNK + c) * HID_ + k];
        } else {
            pv = -3.4e38f;
#pragma unroll
            for (int c = 0; c < PCHUNK; ++c)
                pv = fmaxf(pv, pm2[((size_t)b * PCHUNK + c) * HID_ + (k - HID_)]);
        }
        const float* wp = pW2 + (size_t)k * NC_;
#pragma unroll
        for (int c = 0; c < NC_; ++c) acc[c] += pv * wp[c];
    }
    __shared__ float red[4][NC_];
#pragma unroll
    for (int c = 0; c < NC_; ++c) {
        float s = acc[c];
#pragma unroll
        for (int off = 32; off > 0; off >>= 1) s += __shfl_down(s, off);
        if (lane == 0) red[wv][c] = s;
    }
    __syncthreads();
    if (t < NC_) {
        float s = red[0][t] + red[1][t] + red[2][t] + red[3][t];
        out[b * NC_ + t] = s + pb0[t] + pb1[t] + pb2[t];
    }
}

extern "C" void kernel_launch(void* const* d_in, const int* in_sizes, int n_in,
                              void* d_out, int out_size, void* d_ws, size_t ws_size,
                              hipStream_t stream) {
    const int*   x         = (const int*)d_in[0];
    const int*   inc_rows  = (const int*)d_in[1];
    const int*   inc_cols  = (const int*)d_in[2];
    const float* inc_vals  = (const float*)d_in[3];
    const int*   sent_rows = (const int*)d_in[4];
    const int*   sent_cols = (const int*)d_in[5];
    const float* sent_vals = (const float*)d_in[6];
    const float* deg_v     = (const float*)d_in[7];
    const float* deg_e     = (const float*)d_in[8];
    const float* tf_idf = (const float*)d_in[11];
    const float* emb    = (const float*)d_in[12];
    const float* W1 = (const float*)d_in[13];
    const float* b1 = (const float*)d_in[14];
    const float* W2 = (const float*)d_in[15];
    const float* b2 = (const float*)d_in[16];
    const float* attW0 = (const float*)d_in[17];
    const float* attb0 = (const float*)d_in[18];
    const float* attW1 = (const float*)d_in[19];
    const float* attb1 = (const float*)d_in[20];
    const float* attW2 = (const float*)d_in[21];
    const float* attb2 = (const float*)d_in[22];
    const float* pW0 = (const float*)d_in[23];
    const float* pb0 = (const float*)d_in[24];
    const float* pW1 = (const float*)d_in[25];
    const float* pb1 = (const float*)d_in[26];
    const float* pW2 = (const float*)d_in[27];
    const float* pb2 = (const float*)d_in[28];
    float* out = (float*)d_out;

    // workspace layout
    char* ws = (char*)d_ws;
    size_t off = 0;
    auto alloc = [&](size_t bytes) {
        void* p = ws + off;
        off += (bytes + 255) & ~(size_t)255;
        return p;
    };
    u16* EW = (u16*)alloc((size_t)VOCAB_ * HID_ * sizeof(u16)); // emb @ W1, bf16
    u16* hv = (u16*)alloc((size_t)NV_ * HID_ * sizeof(u16));
    u16* m  = (u16*)alloc((size_t)NE_ * HID_ * sizeof(u16));
    u16* m2 = (u16*)alloc((size_t)NE_ * HID_ * sizeof(u16));
    u16* h1 = (u16*)alloc((size_t)NV_ * HID_ * sizeof(u16));
    u16* h2 = (u16*)alloc((size_t)NV_ * HID_ * sizeof(u16));
    u16* Wt1h = (u16*)alloc((size_t)HID_ * 320 * sizeof(u16));
    u16* Wt1l = (u16*)alloc((size_t)HID_ * 320 * sizeof(u16));
    u16* Wt2h = (u16*)alloc((size_t)HID_ * 256 * sizeof(u16));
    u16* Wt2l = (u16*)alloc((size_t)HID_ * 256 * sizeof(u16));
    float* EA = (float*)alloc((size_t)VOCAB_ * sizeof(float));  // emb @ attW0[:300]
    float* e  = (float*)alloc((size_t)NV_ * sizeof(float));
    float* ps0 = (float*)alloc((size_t)B_ * PCHUNK * D_ * sizeof(float));
    float* pm0 = (float*)alloc((size_t)B_ * PCHUNK * D_ * sizeof(float));
    float* ps1 = (float*)alloc((size_t)B_ * PCHUNK * HID_ * sizeof(float));
    float* pm1 = (float*)alloc((size_t)B_ * PCHUNK * HID_ * sizeof(float));
    float* ps2 = (float*)alloc((size_t)B_ * PCHUNK * HID_ * sizeof(float));
    float* pm2 = (float*)alloc((size_t)B_ * PCHUNK * HID_ * sizeof(float));
    // CSR structures + barrier counters (cnt..bar zeroed by one memset)
    int* cnt  = (int*)alloc((size_t)(SCAN_TOT + 16) * sizeof(int));
    int* bar  = cnt + SCAN_TOT;          // 16 barrier slots
    int* fill = (int*)alloc((size_t)SCAN_TOT * sizeof(int));
    int* rowptr_e = (int*)alloc((size_t)(NE_ + 1) * sizeof(int));
    int* rowptr_v = (int*)alloc((size_t)(NV_ + 1) * sizeof(int));
    int* rowptr_s = (int*)alloc((size_t)(NE_ + 1) * sizeof(int));
    int* bsum  = (int*)alloc((size_t)SCAN_NCH * sizeof(int));
    int* cbase = (int*)alloc((size_t)SCAN_NCH * sizeof(int));
    int4* elist = (int4*)alloc((size_t)NNZ_ * sizeof(int4));
    int2* vlist = (int2*)alloc((size_t)NNZ_ * sizeof(int2));
    int2* slist = (int2*)alloc((size_t)SNNZ_ * sizeof(int2));

    // ---- CSR build + weight conversion: one mega-kernel (software grid barriers) ----
    hipMemsetAsync(cnt, 0, (size_t)(SCAN_TOT + 16) * sizeof(int), stream);
    csr_build_kernel<<<CSR_BLOCKS, 256, 0, stream>>>(
        inc_rows, inc_cols, inc_vals, sent_rows, sent_cols, sent_vals,
        x, deg_e, deg_v, W1, W2, Wt1h, Wt1l, Wt2h, Wt2l,
        cnt, fill, rowptr_e, rowptr_v, rowptr_s, bsum, cbase,
        elist, vlist, slist, bar);

    // ---- EW = emb @ W1 (bf16 out) + EA = emb @ attW0 (free, f32) ----
    gemm_mfma_kernel<true, false, false><<<(VOCAB_ + 63) / 64, 256, 0, stream>>>(
        emb, VOCAB_, D_, D_, Wt1h, Wt1l, 320, nullptr, EW,
        attW0, EA, nullptr, nullptr, nullptr, nullptr);

    // ---- pool layer 0 (fused softmax+partial; logits from EA) ----
    {
        dim3 pg(B_, PCHUNK);
        pool_partial_kernel<true><<<pg, 256, 0, stream>>>(emb, D_, D_, x, EA,
                                                          tf_idf, attW0 + D_, attb0,
                                                          ps0, pm0);
    }

    // ---- layer 1 sparse chain (single kernel, 3 phases) ----
    chain_kernel<2, true><<<CH_BLOCKS, 256, 0, stream>>>(
        rowptr_e, rowptr_s, rowptr_v, elist, slist, vlist,
        EW, m, m2, b1, h1, attW1, attb1, tf_idf, e, bar + 4);

    // ---- pool layer 1 ----
    {
        dim3 pg(B_, PCHUNK);
        pool_partial_kernel<false><<<pg, 256, 0, stream>>>(h1, HID_, HID_, nullptr, e,
                                                           nullptr, nullptr, nullptr,
                                                           ps1, pm1);
    }

    // ---- layer 2 sparse chain ----
    chain_kernel<1, false><<<CH_BLOCKS, 256, 0, stream>>>(
        rowptr_e, rowptr_s, rowptr_v, elist, slist, vlist,
        h1, m, m2, nullptr, hv, nullptr, nullptr, nullptr, nullptr, bar + 6);

    // ---- h2 = relu(hv @ W2 + b2) + e2 logits in epilogue ----
    gemm_mfma_kernel<false, true, true><<<NV_ / 64, 256, 0, stream>>>(
        hv, NV_, HID_, HID_, Wt2h, Wt2l, 256, b2, h2,
        nullptr, nullptr, attW2, attb2, tf_idf, e);

    // ---- pool layer 2 ----
    {
        dim3 pg(B_, PCHUNK);
        pool_partial_kernel<false><<<pg, 256, 0, stream>>>(h2, HID_, HID_, nullptr, e,
                                                           nullptr, nullptr, nullptr,
                                                           ps2, pm2);
    }

    // ---- final (fused combine + GEMV) ----
    final_kernel<<<B_, 256, 0, stream>>>(ps0, pm0, ps1, pm1, ps2, pm2,
                                         pW0, pb0, pW1, pb1, pW2, pb2, out);
}

// Round 14
// 331.072 us; speedup vs baseline: 4.8769x; 4.8769x over previous
//
#include <hip/hip_runtime.h>
#include <cstddef>

#define B_   64
#define N_   512
#define NV_  32768
#define NE_  8192
#define NNZ_ 262144
#define SNNZ_ 24576
#define D_   300
#define HID_ 256
#define NC_  10
#define VOCAB_ 30000
#define PCHUNK 8
#define PVN (N_ / PCHUNK)   // 64 nodes per pool chunk

#define SCAN_TOT (NE_ + NV_ + NE_)      // 49152 counts, contiguous [cnt_e|cnt_v|cnt_s]
#define SCAN_NCH (SCAN_TOT / 1024)      // 48 chunks
#define SEG1_CH  (NE_ / 1024)           // 8  (start of cnt_v chunks)
#define SEG2_CH  ((NE_ + NV_) / 1024)   // 40 (start of cnt_s chunks)

using u16 = unsigned short;
typedef __attribute__((ext_vector_type(8))) short short8;
typedef __attribute__((ext_vector_type(4))) float f32x4;

__device__ __forceinline__ float bf2f(u16 v) {
    union { unsigned int u; float f; } uf;
    uf.u = ((unsigned int)v) << 16;
    return uf.f;
}
__device__ __forceinline__ u16 f2bf(float f) {
    union { float f; unsigned int u; } uf; uf.f = f;
    unsigned int u = uf.u;
    unsigned int r = u + 0x7fffu + ((u >> 16) & 1u);
    return (u16)(r >> 16);
}

// ---------------- CSR build ----------------------------------------------------------
__global__ __launch_bounds__(256) void hist_kernel(const int* __restrict__ inc_rows,
                                                   const int* __restrict__ inc_cols,
                                                   const int* __restrict__ sent_cols,
                                                   int* __restrict__ cnt) {
    int i = blockIdx.x * 256 + threadIdx.x;
    atomicAdd(&cnt[inc_cols[i]], 1);
    atomicAdd(&cnt[NE_ + inc_rows[i]], 1);
    if (i < SNNZ_) atomicAdd(&cnt[NE_ + NV_ + sent_cols[i]], 1);
}

__global__ __launch_bounds__(256) void scanA_kernel(const int* __restrict__ cnt,
                                                    int* __restrict__ bsum) {
    int blk = blockIdx.x, t = threadIdx.x;
    int4 v = reinterpret_cast<const int4*>(cnt)[blk * 256 + t];
    int s = v.x + v.y + v.z + v.w;
    __shared__ int red[256];
    red[t] = s;
    __syncthreads();
    for (int o = 128; o > 0; o >>= 1) {
        if (t < o) red[t] += red[t + o];
        __syncthreads();
    }
    if (t == 0) bsum[blk] = red[0];
}

__global__ __launch_bounds__(64) void scanB_kernel(const int* __restrict__ bsum,
                                                   int* __restrict__ cbase) {
    if (threadIdx.x == 0) {
        int run = 0;
        for (int c = 0; c < SCAN_NCH; ++c) {
            if (c == SEG1_CH || c == SEG2_CH) run = 0;
            cbase[c] = run;
            run += bsum[c];
        }
    }
}

__global__ __launch_bounds__(256) void scanC_kernel(const int* __restrict__ cnt,
                                                    const int* __restrict__ cbase,
                                                    int* __restrict__ rowptr_e,
                                                    int* __restrict__ rowptr_v,
                                                    int* __restrict__ rowptr_s,
                                                    int* __restrict__ fill) {
    int blk = blockIdx.x, t = threadIdx.x;
    int gi = blk * 1024 + t * 4;
    int4 v = reinterpret_cast<const int4*>(cnt)[blk * 256 + t];
    int s0 = v.x, s1 = s0 + v.y, s2 = s1 + v.z, s3 = s2 + v.w;
    __shared__ int part[256];
    part[t] = s3;
    __syncthreads();
    for (int o = 1; o < 256; o <<= 1) {
        int a = (t >= o) ? part[t - o] : 0;
        __syncthreads();
        part[t] += a;
        __syncthreads();
    }
    int excl = (t > 0 ? part[t - 1] : 0) + cbase[blk];
    int4 e;
    e.x = excl; e.y = excl + s0; e.z = excl + s1; e.w = excl + s2;
    int* rp; int li;
    if (blk < SEG1_CH)      { rp = rowptr_e; li = gi; }
    else if (blk < SEG2_CH) { rp = rowptr_v; li = gi - NE_; }
    else                    { rp = rowptr_s; li = gi - NE_ - NV_; }
    rp[li + 0] = e.x; rp[li + 1] = e.y; rp[li + 2] = e.z; rp[li + 3] = e.w;
    reinterpret_cast<int4*>(fill)[blk * 256 + t] = e;
    if (t == 255) {
        int tot = excl + s3;
        if (blk == SEG1_CH - 1) rowptr_e[NE_] = tot;
        if (blk == SEG2_CH - 1) rowptr_v[NV_] = tot;
        if (blk == SCAN_NCH - 1) rowptr_s[NE_] = tot;
    }
}

// packed placement: e-list = int4{node, x[node], valbits, 0}; v/s-list = int2{idx, valbits}
__global__ __launch_bounds__(256) void place_kernel(const int* __restrict__ inc_rows,
                                                    const int* __restrict__ inc_cols,
                                                    const float* __restrict__ inc_vals,
                                                    const int* __restrict__ sent_rows,
                                                    const int* __restrict__ sent_cols,
                                                    const float* __restrict__ sent_vals,
                                                    const int* __restrict__ x,
                                                    const float* __restrict__ deg_e,
                                                    const float* __restrict__ deg_v,
                                                    int* __restrict__ fill,
                                                    int4* __restrict__ elist,
                                                    int2* __restrict__ vlist,
                                                    int2* __restrict__ slist) {
    int i = blockIdx.x * 256 + threadIdx.x;
    int r = inc_rows[i], c = inc_cols[i];
    float v = inc_vals[i];
    int pe = atomicAdd(&fill[c], 1);
    int4 ee;
    ee.x = r; ee.y = x[r];
    ee.z = __float_as_int(v * deg_e[c]); ee.w = 0;
    elist[pe] = ee;
    int pv = atomicAdd(&fill[NE_ + r], 1);
    int2 vv;
    vv.x = c; vv.y = __float_as_int(v * deg_v[r]);
    vlist[pv] = vv;
    if (i < SNNZ_) {
        int ps = atomicAdd(&fill[NE_ + NV_ + sent_cols[i]], 1);
        int2 ss;
        ss.x = sent_rows[i]; ss.y = __float_as_int(sent_vals[i]);
        slist[ps] = ss;
    }
}

// ---------------- 256-dim segment gather-sum, bf16 src/dst ---------------------------
// MODE 0: int2 list {src, val}; MODE 1: int4 list use .x (node); MODE 2: int4 use .y (x[node])
template <int MODE, bool EPI, bool ATT>
__global__ __launch_bounds__(256) void gather256_kernel(const int* __restrict__ rowptr,
                                                        const void* __restrict__ listv,
                                                        const u16* __restrict__ src,
                                                        const float* __restrict__ bias,
                                                        u16* __restrict__ dst, int nseg,
                                                        const float* __restrict__ attW,
                                                        const float* __restrict__ attb,
                                                        const float* __restrict__ tfidf,
                                                        float* __restrict__ e) {
    int seg = (blockIdx.x * 256 + threadIdx.x) >> 6;
    int lane = threadIdx.x & 63;
    if (seg >= nseg) return;
    int start = rowptr[seg], end = rowptr[seg + 1];
    float4 acc = make_float4(0.f, 0.f, 0.f, 0.f);
    for (int k = start; k < end; ++k) {
        int r; float v;
        if constexpr (MODE == 0) {
            int2 q = ((const int2*)listv)[k];
            r = q.x; v = __int_as_float(q.y);
        } else {
            int4 q = ((const int4*)listv)[k];
            r = (MODE == 1) ? q.x : q.y;
            v = __int_as_float(q.z);
        }
        ushort4 sv = *reinterpret_cast<const ushort4*>(src + (size_t)r * 256 + lane * 4);
        acc.x += v * bf2f(sv.x); acc.y += v * bf2f(sv.y);
        acc.z += v * bf2f(sv.z); acc.w += v * bf2f(sv.w);
    }
    float4 o = acc;
    if constexpr (EPI) {
        float4 bv = reinterpret_cast<const float4*>(bias)[lane];
        o.x = fmaxf(o.x + bv.x, 0.f); o.y = fmaxf(o.y + bv.y, 0.f);
        o.z = fmaxf(o.z + bv.z, 0.f); o.w = fmaxf(o.w + bv.w, 0.f);
    }
    ushort4 o4;
    o4.x = f2bf(o.x); o4.y = f2bf(o.y); o4.z = f2bf(o.z); o4.w = f2bf(o.w);
    *reinterpret_cast<ushort4*>(dst + (size_t)seg * 256 + lane * 4) = o4;
    if constexpr (ATT) {
        float4 aw = reinterpret_cast<const float4*>(attW)[lane];
        float pe = o.x * aw.x + o.y * aw.y + o.z * aw.z + o.w * aw.w;
#pragma unroll
        for (int off = 32; off > 0; off >>= 1) pe += __shfl_down(pe, off);
        if (lane == 0)
            e[seg] = pe + tfidf[seg * 2] * attW[HID_] + tfidf[seg * 2 + 1] * attW[HID_ + 1]
                     + attb[0];
    }
}

// ---------------- W -> transposed hi/lo bf16 split (both weights, fused) ------------
__global__ __launch_bounds__(256) void wconv_kernel(const float* __restrict__ W1,
                                                    const float* __restrict__ W2,
                                                    u16* __restrict__ Wt1h, u16* __restrict__ Wt1l,
                                                    u16* __restrict__ Wt2h, u16* __restrict__ Wt2l) {
    int idx = blockIdx.x * 256 + threadIdx.x;
    const float* W; u16 *Wh, *Wl; int K, KP;
    if (idx < 256 * 320) { W = W1; Wh = Wt1h; Wl = Wt1l; K = D_; KP = 320; }
    else { idx -= 256 * 320; if (idx >= 256 * 256) return;
           W = W2; Wh = Wt2h; Wl = Wt2l; K = HID_; KP = 256; }
    int n = idx & 255;
    int k = idx >> 8;
    float v = (k < K) ? W[(size_t)k * HID_ + n] : 0.f;
    u16 hi = f2bf(v);
    u16 lo = f2bf(v - bf2f(hi));
    Wh[(size_t)n * KP + k] = hi;
    Wl[(size_t)n * KP + k] = lo;
}

// ---------------- MFMA GEMM, full-N tile 64x256: C = A @ Wt^T -----------------------
template <bool SPLIT_A, bool EPI, bool ATT>
__global__ __launch_bounds__(256) void gemm_mfma_kernel(const void* __restrict__ Av,
                                                        int M, int K, int Ks,
                                                        const u16* __restrict__ Bth,
                                                        const u16* __restrict__ Btl, int bstride,
                                                        const float* __restrict__ bias,
                                                        void* __restrict__ Cv,
                                                        const float* __restrict__ attWA,
                                                        float* __restrict__ EAp,
                                                        const float* __restrict__ attW,
                                                        const float* __restrict__ attb,
                                                        const float* __restrict__ tfidf,
                                                        float* __restrict__ e) {
    __shared__ __align__(16) u16 Ah[64 * 32];
    __shared__ __align__(16) u16 Al[64 * 32];
    __shared__ __align__(16) u16 Bh[256 * 32];
    __shared__ __align__(16) u16 Bl[256 * 32];
    int tid = threadIdx.x;
    int bm0 = blockIdx.x * 64;
    int w = tid >> 6, l = tid & 63;
    int srow = tid >> 2;
    int skbp = tid & 3;
    int skbl = skbp ^ ((srow >> 1) & 3);
    int arow = bm0 + srow; if (arow >= M) arow = M - 1;
    int sdst = srow * 32 + skbp * 8;
    int frow = w * 16 + (l & 15);
    int akbp = (l >> 4) ^ ((frow >> 1) & 3);

    f32x4 acc[16] = {};
    float ea = 0.f;
    int nkt = (K + 31) / 32;
    for (int kt = 0; kt < nkt; ++kt) {
        if (kt) __syncthreads();
        int kbase = kt * 32 + skbl * 8;
        if constexpr (SPLIT_A) {
            const float* Arow = (const float*)Av + (size_t)arow * Ks;
            float av[8];
            if (kbase + 8 <= K) {
                float4 v0 = *reinterpret_cast<const float4*>(Arow + kbase);
                float4 v1 = *reinterpret_cast<const float4*>(Arow + kbase + 4);
                av[0] = v0.x; av[1] = v0.y; av[2] = v0.z; av[3] = v0.w;
                av[4] = v1.x; av[5] = v1.y; av[6] = v1.z; av[7] = v1.w;
            } else {
#pragma unroll
                for (int ee = 0; ee < 8; ++ee) {
                    int kk = kbase + ee;
                    av[ee] = (kk < K) ? Arow[kk] : 0.f;
                }
            }
            if (EAp) {
#pragma unroll
                for (int ee = 0; ee < 8; ++ee) {
                    int kk = kbase + ee;
                    ea += av[ee] * ((kk < K) ? attWA[kk] : 0.f);
                }
            }
            short8 h8, l8;
#pragma unroll
            for (int ee = 0; ee < 8; ++ee) {
                u16 hi = f2bf(av[ee]);
                h8[ee] = (short)hi;
                l8[ee] = (short)f2bf(av[ee] - bf2f(hi));
            }
            *(short8*)&Ah[sdst] = h8;
            *(short8*)&Al[sdst] = l8;
        } else {
            const u16* Arow = (const u16*)Av + (size_t)arow * Ks;
            *(short8*)&Ah[sdst] = *(const short8*)(Arow + kbase);
        }
#pragma unroll
        for (int i = 0; i < 4; ++i) {
            int br = i * 64 + srow;
            int bkl = skbp ^ ((br >> 1) & 3);
            *(short8*)&Bh[br * 32 + skbp * 8] =
                *(const short8*)(Bth + (size_t)br * bstride + kt * 32 + bkl * 8);
            *(short8*)&Bl[br * 32 + skbp * 8] =
                *(const short8*)(Btl + (size_t)br * bstride + kt * 32 + bkl * 8);
        }
        __syncthreads();
        short8 ah = *(const short8*)&Ah[frow * 32 + akbp * 8];
        short8 al;
        if constexpr (SPLIT_A) al = *(const short8*)&Al[frow * 32 + akbp * 8];
#pragma unroll
        for (int nt = 0; nt < 16; ++nt) {
            int nrow = nt * 16 + (l & 15);
            int bkbp = (l >> 4) ^ ((nrow >> 1) & 3);
            short8 tbh = *(const short8*)&Bh[nrow * 32 + bkbp * 8];
            short8 tbl = *(const short8*)&Bl[nrow * 32 + bkbp * 8];
            acc[nt] = __builtin_amdgcn_mfma_f32_16x16x32_bf16(ah, tbh, acc[nt], 0, 0, 0);
            if constexpr (SPLIT_A)
                acc[nt] = __builtin_amdgcn_mfma_f32_16x16x32_bf16(al, tbh, acc[nt], 0, 0, 0);
            acc[nt] = __builtin_amdgcn_mfma_f32_16x16x32_bf16(ah, tbl, acc[nt], 0, 0, 0);
        }
    }
    if constexpr (SPLIT_A) {
        if (EAp) {
            ea += __shfl_xor(ea, 1);
            ea += __shfl_xor(ea, 2);
            if ((tid & 3) == 0 && bm0 + srow < M) EAp[bm0 + srow] = ea;
        }
    }
#pragma unroll
    for (int r = 0; r < 4; ++r) {
        int row = bm0 + w * 16 + (l >> 4) * 4 + r;
        if (row >= M) continue;
        float er = 0.f;
#pragma unroll
        for (int nt = 0; nt < 16; ++nt) {
            int col = nt * 16 + (l & 15);
            float v = acc[nt][r];
            if constexpr (EPI) {
                v = v + bias[col];
                v = v > 0.f ? v : 0.f;
            }
            if constexpr (ATT) er += v * attW[col];
            ((u16*)Cv)[(size_t)row * 256 + col] = f2bf(v);
        }
        if constexpr (ATT) {
            er += __shfl_xor(er, 1);
            er += __shfl_xor(er, 2);
            er += __shfl_xor(er, 4);
            er += __shfl_xor(er, 8);
            if ((l & 15) == 0)
                e[row] = er + tfidf[row * 2] * attW[HID_] + tfidf[row * 2 + 1] * attW[HID_ + 1]
                         + attb[0];
        }
    }
}

// ---------------- pool partial: fused per-graph softmax + weighted-sum + max --------
template <bool L0>
__global__ __launch_bounds__(256) void pool_partial_kernel(const void* __restrict__ h, int dim,
                                                           int stride,
                                                           const int* __restrict__ x,
                                                           const float* __restrict__ EA_or_e,
                                                           const float* __restrict__ tfidf,
                                                           const float* __restrict__ attWtail,
                                                           const float* __restrict__ attb,
                                                           float* __restrict__ psum,
                                                           float* __restrict__ pmax) {
    int b = blockIdx.x, c = blockIdx.y;
    int t = threadIdx.x;
    __shared__ float sev[N_];
    __shared__ int srows[N_];
    __shared__ float red[256];
    __shared__ float wv[PVN];
    int n0 = b * N_ + t, n1 = n0 + 256;
    float ev0, ev1;
    int r0, r1;
    if constexpr (L0) {
        r0 = x[n0]; r1 = x[n1];
        float a0 = attWtail[0], a1 = attWtail[1], ab = attb[0];
        ev0 = EA_or_e[r0] + tfidf[n0 * 2] * a0 + tfidf[n0 * 2 + 1] * a1 + ab;
        ev1 = EA_or_e[r1] + tfidf[n1 * 2] * a0 + tfidf[n1 * 2 + 1] * a1 + ab;
    } else {
        r0 = n0; r1 = n1;
        ev0 = EA_or_e[n0]; ev1 = EA_or_e[n1];
    }
    sev[t] = ev0; sev[t + 256] = ev1;
    srows[t] = r0; srows[t + 256] = r1;
    red[t] = fmaxf(ev0, ev1);
    __syncthreads();
    for (int s = 128; s > 0; s >>= 1) {
        if (t < s) red[t] = fmaxf(red[t], red[t + s]);
        __syncthreads();
    }
    float mx = red[0];
    __syncthreads();
    red[t] = expf(ev0 - mx) + expf(ev1 - mx);
    __syncthreads();
    for (int s = 128; s > 0; s >>= 1) {
        if (t < s) red[t] += red[t + s];
        __syncthreads();
    }
    float inv = 1.f / (red[0] + 1e-10f);
    if (t < PVN) wv[t] = expf(sev[c * PVN + t] - mx) * inv;
    __syncthreads();
    float s0 = 0.f, s1 = 0.f, m0 = -3.4e38f, m1 = -3.4e38f;
    int d0 = t, d1 = t + 256;
    bool has1 = d1 < dim;
    for (int i = 0; i < PVN; ++i) {
        int row = srows[c * PVN + i];
        float ww = wv[i];
        float x0, x1 = 0.f;
        if constexpr (L0) {
            const float* hp = (const float*)h + (size_t)row * stride;
            x0 = hp[d0];
            if (has1) x1 = hp[d1];
        } else {
            const u16* hp = (const u16*)h + (size_t)row * stride;
            x0 = bf2f(hp[d0]);
            if (has1) x1 = bf2f(hp[d1]);
        }
        s0 += ww * x0;
        m0 = fmaxf(m0, x0);
        if (has1) {
            s1 += ww * x1;
            m1 = fmaxf(m1, x1);
        }
    }
    size_t base = ((size_t)b * PCHUNK + c) * dim;
    psum[base + d0] = s0;
    pmax[base + d0] = m0;
    if (has1) {
        psum[base + d1] = s1;
        pmax[base + d1] = m1;
    }
}

// ---------------- final: combine chunk partials on the fly + GEMV -------------------
__global__ __launch_bounds__(256) void final_kernel(const float* __restrict__ ps0,
                                                    const float* __restrict__ pm0,
                                                    const float* __restrict__ ps1,
                                                    const float* __restrict__ pm1,
                                                    const float* __restrict__ ps2,
                                                    const float* __restrict__ pm2,
                                                    const float* __restrict__ pW0,
                                                    const float* __restrict__ pb0,
                                                    const float* __restrict__ pW1,
                                                    const float* __restrict__ pb1,
                                                    const float* __restrict__ pW2,
                                                    const float* __restrict__ pb2,
                                                    float* __restrict__ out) {
    int b = blockIdx.x;
    int t = threadIdx.x;
    int lane = t & 63, wv = t >> 6;
    float acc[NC_] = {};
    for (int k = t; k < 2 * D_; k += 256) {
        float pv;
        if (k < D_) {
            pv = 0.f;
#pragma unroll
            for (int c = 0; c < PCHUNK; ++c) pv += ps0[((size_t)b * PCHUNK + c) * D_ + k];
        } else {
            pv = -3.4e38f;
#pragma unroll
            for (int c = 0; c < PCHUNK; ++c)
                pv = fmaxf(pv, pm0[((size_t)b * PCHUNK + c) * D_ + (k - D_)]);
        }
        const float* wp = pW0 + (size_t)k * NC_;
#pragma unroll
        for (int c = 0; c < NC_; ++c) acc[c] += pv * wp[c];
    }
    for (int k = t; k < 2 * HID_; k += 256) {
        float pv;
        if (k < HID_) {
            pv = 0.f;
#pragma unroll
            for (int c = 0; c < PCHUNK; ++c) pv += ps1[((size_t)b * PCHUNK + c) * HID_ + k];
        } else {
            pv = -3.4e38f;
#pragma unroll
            for (int c = 0; c < PCHUNK; ++c)
                pv = fmaxf(pv, pm1[((size_t)b * PCHUNK + c) * HID_ + (k - HID_)]);
        }
        const float* wp = pW1 + (size_t)k * NC_;
#pragma unroll
        for (int c = 0; c < NC_; ++c) acc[c] += pv * wp[c];
    }
    for (int k = t; k < 2 * HID_; k += 256) {
        float pv;
        if (k < HID_) {
            pv = 0.f;
#pragma unroll
            for (int c = 0; c < PCHUNK; ++c) pv += ps2[((size_t)b * PCHUNK + c) * HID_ + k];
        } else {
            pv = -3.4e38f;
#pragma unroll
            for (int c = 0; c < PCHUNK; ++c)
                pv = fmaxf(pv, pm2[((size_t)b * PCHUNK + c) * HID_ + (k - HID_)]);
        }
        const float* wp = pW2 + (size_t)k * NC_;
#pragma unroll
        for (int c = 0; c < NC_; ++c) acc[c] += pv * wp[c];
    }
    __shared__ float red[4][NC_];
#pragma unroll
    for (int c = 0; c < NC_; ++c) {
        float s = acc[c];
#pragma unroll
        for (int off = 32; off > 0; off >>= 1) s += __shfl_down(s, off);
        if (lane == 0) red[wv][c] = s;
    }
    __syncthreads();
    if (t < NC_) {
        float s = red[0][t] + red[1][t] + red[2][t] + red[3][t];
        out[b * NC_ + t] = s + pb0[t] + pb1[t] + pb2[t];
    }
}

extern "C" void kernel_launch(void* const* d_in, const int* in_sizes, int n_in,
                              void* d_out, int out_size, void* d_ws, size_t ws_size,
                              hipStream_t stream) {
    const int*   x         = (const int*)d_in[0];
    const int*   inc_rows  = (const int*)d_in[1];
    const int*   inc_cols  = (const int*)d_in[2];
    const float* inc_vals  = (const float*)d_in[3];
    const int*   sent_rows = (const int*)d_in[4];
    const int*   sent_cols = (const int*)d_in[5];
    const float* sent_vals = (const float*)d_in[6];
    const float* deg_v     = (const float*)d_in[7];
    const float* deg_e     = (const float*)d_in[8];
    const float* tf_idf = (const float*)d_in[11];
    const float* emb    = (const float*)d_in[12];
    const float* W1 = (const float*)d_in[13];
    const float* b1 = (const float*)d_in[14];
    const float* W2 = (const float*)d_in[15];
    const float* b2 = (const float*)d_in[16];
    const float* attW0 = (const float*)d_in[17];
    const float* attb0 = (const float*)d_in[18];
    const float* attW1 = (const float*)d_in[19];
    const float* attb1 = (const float*)d_in[20];
    const float* attW2 = (const float*)d_in[21];
    const float* attb2 = (const float*)d_in[22];
    const float* pW0 = (const float*)d_in[23];
    const float* pb0 = (const float*)d_in[24];
    const float* pW1 = (const float*)d_in[25];
    const float* pb1 = (const float*)d_in[26];
    const float* pW2 = (const float*)d_in[27];
    const float* pb2 = (const float*)d_in[28];
    float* out = (float*)d_out;

    // workspace layout
    char* ws = (char*)d_ws;
    size_t off = 0;
    auto alloc = [&](size_t bytes) {
        void* p = ws + off;
        off += (bytes + 255) & ~(size_t)255;
        return p;
    };
    u16* EW = (u16*)alloc((size_t)VOCAB_ * HID_ * sizeof(u16)); // emb @ W1, bf16
    u16* hv = (u16*)alloc((size_t)NV_ * HID_ * sizeof(u16));
    u16* m  = (u16*)alloc((size_t)NE_ * HID_ * sizeof(u16));
    u16* m2 = (u16*)alloc((size_t)NE_ * HID_ * sizeof(u16));
    u16* h1 = (u16*)alloc((size_t)NV_ * HID_ * sizeof(u16));
    u16* h2 = (u16*)alloc((size_t)NV_ * HID_ * sizeof(u16));
    u16* Wt1h = (u16*)alloc((size_t)HID_ * 320 * sizeof(u16));
    u16* Wt1l = (u16*)alloc((size_t)HID_ * 320 * sizeof(u16));
    u16* Wt2h = (u16*)alloc((size_t)HID_ * 256 * sizeof(u16));
    u16* Wt2l = (u16*)alloc((size_t)HID_ * 256 * sizeof(u16));
    float* EA = (float*)alloc((size_t)VOCAB_ * sizeof(float));  // emb @ attW0[:300]
    float* e  = (float*)alloc((size_t)NV_ * sizeof(float));
    float* ps0 = (float*)alloc((size_t)B_ * PCHUNK * D_ * sizeof(float));
    float* pm0 = (float*)alloc((size_t)B_ * PCHUNK * D_ * sizeof(float));
    float* ps1 = (float*)alloc((size_t)B_ * PCHUNK * HID_ * sizeof(float));
    float* pm1 = (float*)alloc((size_t)B_ * PCHUNK * HID_ * sizeof(float));
    float* ps2 = (float*)alloc((size_t)B_ * PCHUNK * HID_ * sizeof(float));
    float* pm2 = (float*)alloc((size_t)B_ * PCHUNK * HID_ * sizeof(float));
    // CSR structures
    int* cnt  = (int*)alloc((size_t)SCAN_TOT * sizeof(int));  // [cnt_e|cnt_v|cnt_s]
    int* fill = (int*)alloc((size_t)SCAN_TOT * sizeof(int));
    int* rowptr_e = (int*)alloc((size_t)(NE_ + 1) * sizeof(int));
    int* rowptr_v = (int*)alloc((size_t)(NV_ + 1) * sizeof(int));
    int* rowptr_s = (int*)alloc((size_t)(NE_ + 1) * sizeof(int));
    int* bsum  = (int*)alloc((size_t)SCAN_NCH * sizeof(int));
    int* cbase = (int*)alloc((size_t)SCAN_NCH * sizeof(int));
    int4* elist = (int4*)alloc((size_t)NNZ_ * sizeof(int4));
    int2* vlist = (int2*)alloc((size_t)NNZ_ * sizeof(int2));
    int2* slist = (int2*)alloc((size_t)SNNZ_ * sizeof(int2));

    // ---- build CSR (fused hist / scan / packed place with deg folding) ----
    hipMemsetAsync(cnt, 0, (size_t)SCAN_TOT * sizeof(int), stream);
    hist_kernel<<<NNZ_ / 256, 256, 0, stream>>>(inc_rows, inc_cols, sent_cols, cnt);
    scanA_kernel<<<SCAN_NCH, 256, 0, stream>>>(cnt, bsum);
    scanB_kernel<<<1, 64, 0, stream>>>(bsum, cbase);
    scanC_kernel<<<SCAN_NCH, 256, 0, stream>>>(cnt, cbase, rowptr_e, rowptr_v, rowptr_s, fill);
    place_kernel<<<NNZ_ / 256, 256, 0, stream>>>(inc_rows, inc_cols, inc_vals,
                                                 sent_rows, sent_cols, sent_vals,
                                                 x, deg_e, deg_v, fill,
                                                 elist, vlist, slist);

    // ---- weight conversion (both layers, one launch) ----
    wconv_kernel<<<(256 * 320 + 256 * 256 + 255) / 256, 256, 0, stream>>>(
        W1, W2, Wt1h, Wt1l, Wt2h, Wt2l);

    // ---- EW = emb @ W1 (bf16 out) + EA = emb @ attW0 (free, f32) ----
    gemm_mfma_kernel<true, false, false><<<(VOCAB_ + 63) / 64, 256, 0, stream>>>(
        emb, VOCAB_, D_, D_, Wt1h, Wt1l, 320, nullptr, EW,
        attW0, EA, nullptr, nullptr, nullptr, nullptr);

    // ---- pool layer 0 (fused softmax+partial; logits from EA) ----
    {
        dim3 pg(B_, PCHUNK);
        pool_partial_kernel<true><<<pg, 256, 0, stream>>>(emb, D_, D_, x, EA,
                                                          tf_idf, attW0 + D_, attb0,
                                                          ps0, pm0);
    }

    // ---- layer 1 sparse chain @ dim 256 (deg folded into vals) ----
    gather256_kernel<2, false, false><<<NE_ / 4, 256, 0, stream>>>(
        rowptr_e, elist, EW, nullptr, m, NE_, nullptr, nullptr, nullptr, nullptr);
    gather256_kernel<0, false, false><<<NE_ / 4, 256, 0, stream>>>(
        rowptr_s, slist, m, nullptr, m2, NE_, nullptr, nullptr, nullptr, nullptr);
    gather256_kernel<0, true, true><<<NV_ / 4, 256, 0, stream>>>(
        rowptr_v, vlist, m2, b1, h1, NV_, attW1, attb1, tf_idf, e);

    // ---- pool layer 1 ----
    {
        dim3 pg(B_, PCHUNK);
        pool_partial_kernel<false><<<pg, 256, 0, stream>>>(h1, HID_, HID_, nullptr, e,
                                                           nullptr, nullptr, nullptr,
                                                           ps1, pm1);
    }

    // ---- layer 2 ----
    gather256_kernel<1, false, false><<<NE_ / 4, 256, 0, stream>>>(
        rowptr_e, elist, h1, nullptr, m, NE_, nullptr, nullptr, nullptr, nullptr);
    gather256_kernel<0, false, false><<<NE_ / 4, 256, 0, stream>>>(
        rowptr_s, slist, m, nullptr, m2, NE_, nullptr, nullptr, nullptr, nullptr);
    gather256_kernel<0, false, false><<<NV_ / 4, 256, 0, stream>>>(
        rowptr_v, vlist, m2, nullptr, hv, NV_, nullptr, nullptr, nullptr, nullptr);
    // h2 = relu(hv @ W2 + b2) (deg_v already in hv) + e2 logits in epilogue
    gemm_mfma_kernel<false, true, true><<<NV_ / 64, 256, 0, stream>>>(
        hv, NV_, HID_, HID_, Wt2h, Wt2l, 256, b2, h2,
        nullptr, nullptr, attW2, attb2, tf_idf, e);

    // ---- pool layer 2 ----
    {
        dim3 pg(B_, PCHUNK);
        pool_partial_kernel<false><<<pg, 256, 0, stream>>>(h2, HID_, HID_, nullptr, e,
                                                           nullptr, nullptr, nullptr,
                                                           ps2, pm2);
    }

    // ---- final (fused combine + GEMV) ----
    final_kernel<<<B_, 256, 0, stream>>>(ps0, pm0, ps1, pm1, ps2, pm2,
                                         pW0, pb0, pW1, pb1, pW2, pb2, out);
}

// Round 15
// 322.777 us; speedup vs baseline: 5.0023x; 1.0257x over previous
//
#include <hip/hip_runtime.h>
#include <cstddef>

#define B_   64
#define N_   512
#define NV_  32768
#define NE_  8192
#define NNZ_ 262144
#define SNNZ_ 24576
#define D_   300
#define HID_ 256
#define NC_  10
#define VOCAB_ 30000
#define PCHUNK 8
#define PVN (N_ / PCHUNK)   // 64 nodes per pool chunk

#define SCAN_TOT (NE_ + NV_ + NE_)      // 49152 counts, contiguous [cnt_e|cnt_v|cnt_s]
#define SCAN_NCH (SCAN_TOT / 1024)      // 48 chunks
#define SEG1_CH  (NE_ / 1024)           // 8  (start of cnt_v chunks)
#define SEG2_CH  ((NE_ + NV_) / 1024)   // 40 (start of cnt_s chunks)
#define WCONV_TOT (256 * 320 + 256 * 256)

using u16 = unsigned short;
typedef __attribute__((ext_vector_type(8))) short short8;
typedef __attribute__((ext_vector_type(4))) float f32x4;

__device__ __forceinline__ float bf2f(u16 v) {
    union { unsigned int u; float f; } uf;
    uf.u = ((unsigned int)v) << 16;
    return uf.f;
}
__device__ __forceinline__ u16 f2bf(float f) {
    union { float f; unsigned int u; } uf; uf.f = f;
    unsigned int u = uf.u;
    unsigned int r = u + 0x7fffu + ((u >> 16) & 1u);
    return (u16)(r >> 16);
}

// ---------------- CSR build + weight conversion -------------------------------------
// hist for all three segment lists + wconv (independent work) in one launch
__global__ __launch_bounds__(256) void hist_wconv_kernel(const int* __restrict__ inc_rows,
                                                         const int* __restrict__ inc_cols,
                                                         const int* __restrict__ sent_cols,
                                                         int* __restrict__ cnt,
                                                         const float* __restrict__ W1,
                                                         const float* __restrict__ W2,
                                                         u16* __restrict__ Wt1h,
                                                         u16* __restrict__ Wt1l,
                                                         u16* __restrict__ Wt2h,
                                                         u16* __restrict__ Wt2l) {
    int i = blockIdx.x * 256 + threadIdx.x;
    atomicAdd(&cnt[inc_cols[i]], 1);
    atomicAdd(&cnt[NE_ + inc_rows[i]], 1);
    if (i < SNNZ_) atomicAdd(&cnt[NE_ + NV_ + sent_cols[i]], 1);
    if (i < WCONV_TOT) {
        int id = i;
        const float* W; u16 *Wh, *Wl; int K, KP;
        if (id < 256 * 320) { W = W1; Wh = Wt1h; Wl = Wt1l; K = D_; KP = 320; }
        else { id -= 256 * 320; W = W2; Wh = Wt2h; Wl = Wt2l; K = HID_; KP = 256; }
        int n = id & 255, k = id >> 8;
        float v = (k < K) ? W[(size_t)k * HID_ + n] : 0.f;
        u16 hi = f2bf(v);
        Wh[(size_t)n * KP + k] = hi;
        Wl[(size_t)n * KP + k] = f2bf(v - bf2f(hi));
    }
}

__global__ __launch_bounds__(256) void scanA_kernel(const int* __restrict__ cnt,
                                                    int* __restrict__ bsum) {
    int blk = blockIdx.x, t = threadIdx.x;
    int4 v = reinterpret_cast<const int4*>(cnt)[blk * 256 + t];
    int s = v.x + v.y + v.z + v.w;
    __shared__ int red[256];
    red[t] = s;
    __syncthreads();
    for (int o = 128; o > 0; o >>= 1) {
        if (t < o) red[t] += red[t + o];
        __syncthreads();
    }
    if (t == 0) bsum[blk] = red[0];
}

// scanC with inline chunk-base computation (scanB folded in; <=48 uniform adds)
__global__ __launch_bounds__(256) void scanC_kernel(const int* __restrict__ cnt,
                                                    const int* __restrict__ bsum,
                                                    int* __restrict__ rowptr_e,
                                                    int* __restrict__ rowptr_v,
                                                    int* __restrict__ rowptr_s,
                                                    int* __restrict__ fill) {
    int blk = blockIdx.x, t = threadIdx.x;
    int segstart = (blk < SEG1_CH) ? 0 : ((blk < SEG2_CH) ? SEG1_CH : SEG2_CH);
    int cbase = 0;
    for (int c = segstart; c < blk; ++c) cbase += bsum[c];
    int gi = blk * 1024 + t * 4;
    int4 v = reinterpret_cast<const int4*>(cnt)[blk * 256 + t];
    int s0 = v.x, s1 = s0 + v.y, s2 = s1 + v.z, s3 = s2 + v.w;
    __shared__ int part[256];
    part[t] = s3;
    __syncthreads();
    for (int o = 1; o < 256; o <<= 1) {
        int a = (t >= o) ? part[t - o] : 0;
        __syncthreads();
        part[t] += a;
        __syncthreads();
    }
    int excl = (t > 0 ? part[t - 1] : 0) + cbase;
    int4 e;
    e.x = excl; e.y = excl + s0; e.z = excl + s1; e.w = excl + s2;
    int* rp; int li;
    if (blk < SEG1_CH)      { rp = rowptr_e; li = gi; }
    else if (blk < SEG2_CH) { rp = rowptr_v; li = gi - NE_; }
    else                    { rp = rowptr_s; li = gi - NE_ - NV_; }
    rp[li + 0] = e.x; rp[li + 1] = e.y; rp[li + 2] = e.z; rp[li + 3] = e.w;
    reinterpret_cast<int4*>(fill)[blk * 256 + t] = e;
    if (t == 255) {
        int tot = excl + s3;
        if (blk == SEG1_CH - 1) rowptr_e[NE_] = tot;
        if (blk == SEG2_CH - 1) rowptr_v[NV_] = tot;
        if (blk == SCAN_NCH - 1) rowptr_s[NE_] = tot;
    }
}

// packed placement: e-list = int4{node, x[node], valbits, 0}; v/s-list = int2{idx, valbits}
__global__ __launch_bounds__(256) void place_kernel(const int* __restrict__ inc_rows,
                                                    const int* __restrict__ inc_cols,
                                                    const float* __restrict__ inc_vals,
                                                    const int* __restrict__ sent_rows,
                                                    const int* __restrict__ sent_cols,
                                                    const float* __restrict__ sent_vals,
                                                    const int* __restrict__ x,
                                                    const float* __restrict__ deg_e,
                                                    const float* __restrict__ deg_v,
                                                    int* __restrict__ fill,
                                                    int4* __restrict__ elist,
                                                    int2* __restrict__ vlist,
                                                    int2* __restrict__ slist) {
    int i = blockIdx.x * 256 + threadIdx.x;
    int r = inc_rows[i], c = inc_cols[i];
    float v = inc_vals[i];
    int pe = atomicAdd(&fill[c], 1);
    int4 ee;
    ee.x = r; ee.y = x[r];
    ee.z = __float_as_int(v * deg_e[c]); ee.w = 0;
    elist[pe] = ee;
    int pv = atomicAdd(&fill[NE_ + r], 1);
    int2 vv;
    vv.x = c; vv.y = __float_as_int(v * deg_v[r]);
    vlist[pv] = vv;
    if (i < SNNZ_) {
        int ps = atomicAdd(&fill[NE_ + NV_ + sent_cols[i]], 1);
        int2 ss;
        ss.x = sent_rows[i]; ss.y = __float_as_int(sent_vals[i]);
        slist[ps] = ss;
    }
}

// ---------------- 256-dim segment gather-sum, bf16 src/dst ---------------------------
// MODE 0: int2 list {src, val}; MODE 1: int4 list use .x (node); MODE 2: int4 use .y (x[node])
template <int MODE, bool EPI, bool ATT>
__global__ __launch_bounds__(256) void gather256_kernel(const int* __restrict__ rowptr,
                                                        const void* __restrict__ listv,
                                                        const u16* __restrict__ src,
                                                        const float* __restrict__ bias,
                                                        u16* __restrict__ dst, int nseg,
                                                        const float* __restrict__ attW,
                                                        const float* __restrict__ attb,
                                                        const float* __restrict__ tfidf,
                                                        float* __restrict__ e) {
    int seg = (blockIdx.x * 256 + threadIdx.x) >> 6;
    int lane = threadIdx.x & 63;
    if (seg >= nseg) return;
    int start = rowptr[seg], end = rowptr[seg + 1];
    float4 acc = make_float4(0.f, 0.f, 0.f, 0.f);
    for (int k = start; k < end; ++k) {
        int r; float v;
        if constexpr (MODE == 0) {
            int2 q = ((const int2*)listv)[k];
            r = q.x; v = __int_as_float(q.y);
        } else {
            int4 q = ((const int4*)listv)[k];
            r = (MODE == 1) ? q.x : q.y;
            v = __int_as_float(q.z);
        }
        ushort4 sv = *reinterpret_cast<const ushort4*>(src + (size_t)r * 256 + lane * 4);
        acc.x += v * bf2f(sv.x); acc.y += v * bf2f(sv.y);
        acc.z += v * bf2f(sv.z); acc.w += v * bf2f(sv.w);
    }
    float4 o = acc;
    if constexpr (EPI) {
        float4 bv = reinterpret_cast<const float4*>(bias)[lane];
        o.x = fmaxf(o.x + bv.x, 0.f); o.y = fmaxf(o.y + bv.y, 0.f);
        o.z = fmaxf(o.z + bv.z, 0.f); o.w = fmaxf(o.w + bv.w, 0.f);
    }
    ushort4 o4;
    o4.x = f2bf(o.x); o4.y = f2bf(o.y); o4.z = f2bf(o.z); o4.w = f2bf(o.w);
    *reinterpret_cast<ushort4*>(dst + (size_t)seg * 256 + lane * 4) = o4;
    if constexpr (ATT) {
        float4 aw = reinterpret_cast<const float4*>(attW)[lane];
        float pe = o.x * aw.x + o.y * aw.y + o.z * aw.z + o.w * aw.w;
#pragma unroll
        for (int off = 32; off > 0; off >>= 1) pe += __shfl_down(pe, off);
        if (lane == 0)
            e[seg] = pe + tfidf[seg * 2] * attW[HID_] + tfidf[seg * 2 + 1] * attW[HID_ + 1]
                     + attb[0];
    }
}

// ---------------- MFMA GEMM, full-N tile 64x256: C = A @ Wt^T -----------------------
template <bool SPLIT_A, bool EPI, bool ATT>
__global__ __launch_bounds__(256) void gemm_mfma_kernel(const void* __restrict__ Av,
                                                        int M, int K, int Ks,
                                                        const u16* __restrict__ Bth,
                                                        const u16* __restrict__ Btl, int bstride,
                                                        const float* __restrict__ bias,
                                                        void* __restrict__ Cv,
                                                        const float* __restrict__ attWA,
                                                        float* __restrict__ EAp,
                                                        const float* __restrict__ attW,
                                                        const float* __restrict__ attb,
                                                        const float* __restrict__ tfidf,
                                                        float* __restrict__ e) {
    __shared__ __align__(16) u16 Ah[64 * 32];
    __shared__ __align__(16) u16 Al[64 * 32];
    __shared__ __align__(16) u16 Bh[256 * 32];
    __shared__ __align__(16) u16 Bl[256 * 32];
    int tid = threadIdx.x;
    int bm0 = blockIdx.x * 64;
    int w = tid >> 6, l = tid & 63;
    int srow = tid >> 2;
    int skbp = tid & 3;
    int skbl = skbp ^ ((srow >> 1) & 3);
    int arow = bm0 + srow; if (arow >= M) arow = M - 1;
    int sdst = srow * 32 + skbp * 8;
    int frow = w * 16 + (l & 15);
    int akbp = (l >> 4) ^ ((frow >> 1) & 3);

    f32x4 acc[16] = {};
    float ea = 0.f;
    int nkt = (K + 31) / 32;
    for (int kt = 0; kt < nkt; ++kt) {
        if (kt) __syncthreads();
        int kbase = kt * 32 + skbl * 8;
        if constexpr (SPLIT_A) {
            const float* Arow = (const float*)Av + (size_t)arow * Ks;
            float av[8];
            if (kbase + 8 <= K) {
                float4 v0 = *reinterpret_cast<const float4*>(Arow + kbase);
                float4 v1 = *reinterpret_cast<const float4*>(Arow + kbase + 4);
                av[0] = v0.x; av[1] = v0.y; av[2] = v0.z; av[3] = v0.w;
                av[4] = v1.x; av[5] = v1.y; av[6] = v1.z; av[7] = v1.w;
            } else {
#pragma unroll
                for (int ee = 0; ee < 8; ++ee) {
                    int kk = kbase + ee;
                    av[ee] = (kk < K) ? Arow[kk] : 0.f;
                }
            }
            if (EAp) {
#pragma unroll
                for (int ee = 0; ee < 8; ++ee) {
                    int kk = kbase + ee;
                    ea += av[ee] * ((kk < K) ? attWA[kk] : 0.f);
                }
            }
            short8 h8, l8;
#pragma unroll
            for (int ee = 0; ee < 8; ++ee) {
                u16 hi = f2bf(av[ee]);
                h8[ee] = (short)hi;
                l8[ee] = (short)f2bf(av[ee] - bf2f(hi));
            }
            *(short8*)&Ah[sdst] = h8;
            *(short8*)&Al[sdst] = l8;
        } else {
            const u16* Arow = (const u16*)Av + (size_t)arow * Ks;
            *(short8*)&Ah[sdst] = *(const short8*)(Arow + kbase);
        }
#pragma unroll
        for (int i = 0; i < 4; ++i) {
            int br = i * 64 + srow;
            int bkl = skbp ^ ((br >> 1) & 3);
            *(short8*)&Bh[br * 32 + skbp * 8] =
                *(const short8*)(Bth + (size_t)br * bstride + kt * 32 + bkl * 8);
            *(short8*)&Bl[br * 32 + skbp * 8] =
                *(const short8*)(Btl + (size_t)br * bstride + kt * 32 + bkl * 8);
        }
        __syncthreads();
        short8 ah = *(const short8*)&Ah[frow * 32 + akbp * 8];
        short8 al;
        if constexpr (SPLIT_A) al = *(const short8*)&Al[frow * 32 + akbp * 8];
#pragma unroll
        for (int nt = 0; nt < 16; ++nt) {
            int nrow = nt * 16 + (l & 15);
            int bkbp = (l >> 4) ^ ((nrow >> 1) & 3);
            short8 tbh = *(const short8*)&Bh[nrow * 32 + bkbp * 8];
            short8 tbl = *(const short8*)&Bl[nrow * 32 + bkbp * 8];
            acc[nt] = __builtin_amdgcn_mfma_f32_16x16x32_bf16(ah, tbh, acc[nt], 0, 0, 0);
            if constexpr (SPLIT_A)
                acc[nt] = __builtin_amdgcn_mfma_f32_16x16x32_bf16(al, tbh, acc[nt], 0, 0, 0);
            acc[nt] = __builtin_amdgcn_mfma_f32_16x16x32_bf16(ah, tbl, acc[nt], 0, 0, 0);
        }
    }
    if constexpr (SPLIT_A) {
        if (EAp) {
            ea += __shfl_xor(ea, 1);
            ea += __shfl_xor(ea, 2);
            if ((tid & 3) == 0 && bm0 + srow < M) EAp[bm0 + srow] = ea;
        }
    }
#pragma unroll
    for (int r = 0; r < 4; ++r) {
        int row = bm0 + w * 16 + (l >> 4) * 4 + r;
        if (row >= M) continue;
        float er = 0.f;
#pragma unroll
        for (int nt = 0; nt < 16; ++nt) {
            int col = nt * 16 + (l & 15);
            float v = acc[nt][r];
            if constexpr (EPI) {
                v = v + bias[col];
                v = v > 0.f ? v : 0.f;
            }
            if constexpr (ATT) er += v * attW[col];
            ((u16*)Cv)[(size_t)row * 256 + col] = f2bf(v);
        }
        if constexpr (ATT) {
            er += __shfl_xor(er, 1);
            er += __shfl_xor(er, 2);
            er += __shfl_xor(er, 4);
            er += __shfl_xor(er, 8);
            if ((l & 15) == 0)
                e[row] = er + tfidf[row * 2] * attW[HID_] + tfidf[row * 2 + 1] * attW[HID_ + 1]
                         + attb[0];
        }
    }
}

// ---------------- pool partial: fused per-graph softmax + weighted-sum + max --------
template <bool L0>
__global__ __launch_bounds__(256) void pool_partial_kernel(const void* __restrict__ h, int dim,
                                                           int stride,
                                                           const int* __restrict__ x,
                                                           const float* __restrict__ EA_or_e,
                                                           const float* __restrict__ tfidf,
                                                           const float* __restrict__ attWtail,
                                                           const float* __restrict__ attb,
                                                           float* __restrict__ psum,
                                                           float* __restrict__ pmax) {
    int b = blockIdx.x, c = blockIdx.y;
    int t = threadIdx.x;
    __shared__ float sev[N_];
    __shared__ int srows[N_];
    __shared__ float red[256];
    __shared__ float wv[PVN];
    int n0 = b * N_ + t, n1 = n0 + 256;
    float ev0, ev1;
    int r0, r1;
    if constexpr (L0) {
        r0 = x[n0]; r1 = x[n1];
        float a0 = attWtail[0], a1 = attWtail[1], ab = attb[0];
        ev0 = EA_or_e[r0] + tfidf[n0 * 2] * a0 + tfidf[n0 * 2 + 1] * a1 + ab;
        ev1 = EA_or_e[r1] + tfidf[n1 * 2] * a0 + tfidf[n1 * 2 + 1] * a1 + ab;
    } else {
        r0 = n0; r1 = n1;
        ev0 = EA_or_e[n0]; ev1 = EA_or_e[n1];
    }
    sev[t] = ev0; sev[t + 256] = ev1;
    srows[t] = r0; srows[t + 256] = r1;
    red[t] = fmaxf(ev0, ev1);
    __syncthreads();
    for (int s = 128; s > 0; s >>= 1) {
        if (t < s) red[t] = fmaxf(red[t], red[t + s]);
        __syncthreads();
    }
    float mx = red[0];
    __syncthreads();
    red[t] = expf(ev0 - mx) + expf(ev1 - mx);
    __syncthreads();
    for (int s = 128; s > 0; s >>= 1) {
        if (t < s) red[t] += red[t + s];
        __syncthreads();
    }
    float inv = 1.f / (red[0] + 1e-10f);
    if (t < PVN) wv[t] = expf(sev[c * PVN + t] - mx) * inv;
    __syncthreads();
    float s0 = 0.f, s1 = 0.f, m0 = -3.4e38f, m1 = -3.4e38f;
    int d0 = t, d1 = t + 256;
    bool has1 = d1 < dim;
    for (int i = 0; i < PVN; ++i) {
        int row = srows[c * PVN + i];
        float ww = wv[i];
        float x0, x1 = 0.f;
        if constexpr (L0) {
            const float* hp = (const float*)h + (size_t)row * stride;
            x0 = hp[d0];
            if (has1) x1 = hp[d1];
        } else {
            const u16* hp = (const u16*)h + (size_t)row * stride;
            x0 = bf2f(hp[d0]);
            if (has1) x1 = bf2f(hp[d1]);
        }
        s0 += ww * x0;
        m0 = fmaxf(m0, x0);
        if (has1) {
            s1 += ww * x1;
            m1 = fmaxf(m1, x1);
        }
    }
    size_t base = ((size_t)b * PCHUNK + c) * dim;
    psum[base + d0] = s0;
    pmax[base + d0] = m0;
    if (has1) {
        psum[base + d1] = s1;
        pmax[base + d1] = m1;
    }
}

// ---------------- final: combine chunk partials on the fly + GEMV -------------------
__global__ __launch_bounds__(256) void final_kernel(const float* __restrict__ ps0,
                                                    const float* __restrict__ pm0,
                                                    const float* __restrict__ ps1,
                                                    const float* __restrict__ pm1,
                                                    const float* __restrict__ ps2,
                                                    const float* __restrict__ pm2,
                                                    const float* __restrict__ pW0,
                                                    const float* __restrict__ pb0,
                                                    const float* __restrict__ pW1,
                                                    const float* __restrict__ pb1,
                                                    const float* __restrict__ pW2,
                                                    const float* __restrict__ pb2,
                                                    float* __restrict__ out) {
    int b = blockIdx.x;
    int t = threadIdx.x;
    int lane = t & 63, wv = t >> 6;
    float acc[NC_] = {};
    for (int k = t; k < 2 * D_; k += 256) {
        float pv;
        if (k < D_) {
            pv = 0.f;
#pragma unroll
            for (int c = 0; c < PCHUNK; ++c) pv += ps0[((size_t)b * PCHUNK + c) * D_ + k];
        } else {
            pv = -3.4e38f;
#pragma unroll
            for (int c = 0; c < PCHUNK; ++c)
                pv = fmaxf(pv, pm0[((size_t)b * PCHUNK + c) * D_ + (k - D_)]);
        }
        const float* wp = pW0 + (size_t)k * NC_;
#pragma unroll
        for (int c = 0; c < NC_; ++c) acc[c] += pv * wp[c];
    }
    for (int k = t; k < 2 * HID_; k += 256) {
        float pv;
        if (k < HID_) {
            pv = 0.f;
#pragma unroll
            for (int c = 0; c < PCHUNK; ++c) pv += ps1[((size_t)b * PCHUNK + c) * HID_ + k];
        } else {
            pv = -3.4e38f;
#pragma unroll
            for (int c = 0; c < PCHUNK; ++c)
                pv = fmaxf(pv, pm1[((size_t)b * PCHUNK + c) * HID_ + (k - HID_)]);
        }
        const float* wp = pW1 + (size_t)k * NC_;
#pragma unroll
        for (int c = 0; c < NC_; ++c) acc[c] += pv * wp[c];
    }
    for (int k = t; k < 2 * HID_; k += 256) {
        float pv;
        if (k < HID_) {
            pv = 0.f;
#pragma unroll
            for (int c = 0; c < PCHUNK; ++c) pv += ps2[((size_t)b * PCHUNK + c) * HID_ + k];
        } else {
            pv = -3.4e38f;
#pragma unroll
            for (int c = 0; c < PCHUNK; ++c)
                pv = fmaxf(pv, pm2[((size_t)b * PCHUNK + c) * HID_ + (k - HID_)]);
        }
        const float* wp = pW2 + (size_t)k * NC_;
#pragma unroll
        for (int c = 0; c < NC_; ++c) acc[c] += pv * wp[c];
    }
    __shared__ float red[4][NC_];
#pragma unroll
    for (int c = 0; c < NC_; ++c) {
        float s = acc[c];
#pragma unroll
        for (int off = 32; off > 0; off >>= 1) s += __shfl_down(s, off);
        if (lane == 0) red[wv][c] = s;
    }
    __syncthreads();
    if (t < NC_) {
        float s = red[0][t] + red[1][t] + red[2][t] + red[3][t];
        out[b * NC_ + t] = s + pb0[t] + pb1[t] + pb2[t];
    }
}

extern "C" void kernel_launch(void* const* d_in, const int* in_sizes, int n_in,
                              void* d_out, int out_size, void* d_ws, size_t ws_size,
                              hipStream_t stream) {
    const int*   x         = (const int*)d_in[0];
    const int*   inc_rows  = (const int*)d_in[1];
    const int*   inc_cols  = (const int*)d_in[2];
    const float* inc_vals  = (const float*)d_in[3];
    const int*   sent_rows = (const int*)d_in[4];
    const int*   sent_cols = (const int*)d_in[5];
    const float* sent_vals = (const float*)d_in[6];
    const float* deg_v     = (const float*)d_in[7];
    const float* deg_e     = (const float*)d_in[8];
    const float* tf_idf = (const float*)d_in[11];
    const float* emb    = (const float*)d_in[12];
    const float* W1 = (const float*)d_in[13];
    const float* b1 = (const float*)d_in[14];
    const float* W2 = (const float*)d_in[15];
    const float* b2 = (const float*)d_in[16];
    const float* attW0 = (const float*)d_in[17];
    const float* attb0 = (const float*)d_in[18];
    const float* attW1 = (const float*)d_in[19];
    const float* attb1 = (const float*)d_in[20];
    const float* attW2 = (const float*)d_in[21];
    const float* attb2 = (const float*)d_in[22];
    const float* pW0 = (const float*)d_in[23];
    const float* pb0 = (const float*)d_in[24];
    const float* pW1 = (const float*)d_in[25];
    const float* pb1 = (const float*)d_in[26];
    const float* pW2 = (const float*)d_in[27];
    const float* pb2 = (const float*)d_in[28];
    float* out = (float*)d_out;

    // workspace layout
    char* ws = (char*)d_ws;
    size_t off = 0;
    auto alloc = [&](size_t bytes) {
        void* p = ws + off;
        off += (bytes + 255) & ~(size_t)255;
        return p;
    };
    u16* EW = (u16*)alloc((size_t)VOCAB_ * HID_ * sizeof(u16)); // emb @ W1, bf16
    u16* MW = (u16*)alloc((size_t)NE_ * HID_ * sizeof(u16));    // m2 @ W2, bf16
    u16* m  = (u16*)alloc((size_t)NE_ * HID_ * sizeof(u16));
    u16* m2 = (u16*)alloc((size_t)NE_ * HID_ * sizeof(u16));
    u16* h1 = (u16*)alloc((size_t)NV_ * HID_ * sizeof(u16));
    u16* h2 = (u16*)alloc((size_t)NV_ * HID_ * sizeof(u16));
    u16* Wt1h = (u16*)alloc((size_t)HID_ * 320 * sizeof(u16));
    u16* Wt1l = (u16*)alloc((size_t)HID_ * 320 * sizeof(u16));
    u16* Wt2h = (u16*)alloc((size_t)HID_ * 256 * sizeof(u16));
    u16* Wt2l = (u16*)alloc((size_t)HID_ * 256 * sizeof(u16));
    float* EA = (float*)alloc((size_t)VOCAB_ * sizeof(float));  // emb @ attW0[:300]
    float* e  = (float*)alloc((size_t)NV_ * sizeof(float));
    float* ps0 = (float*)alloc((size_t)B_ * PCHUNK * D_ * sizeof(float));
    float* pm0 = (float*)alloc((size_t)B_ * PCHUNK * D_ * sizeof(float));
    float* ps1 = (float*)alloc((size_t)B_ * PCHUNK * HID_ * sizeof(float));
    float* pm1 = (float*)alloc((size_t)B_ * PCHUNK * HID_ * sizeof(float));
    float* ps2 = (float*)alloc((size_t)B_ * PCHUNK * HID_ * sizeof(float));
    float* pm2 = (float*)alloc((size_t)B_ * PCHUNK * HID_ * sizeof(float));
    // CSR structures
    int* cnt  = (int*)alloc((size_t)SCAN_TOT * sizeof(int));  // [cnt_e|cnt_v|cnt_s]
    int* fill = (int*)alloc((size_t)SCAN_TOT * sizeof(int));
    int* rowptr_e = (int*)alloc((size_t)(NE_ + 1) * sizeof(int));
    int* rowptr_v = (int*)alloc((size_t)(NV_ + 1) * sizeof(int));
    int* rowptr_s = (int*)alloc((size_t)(NE_ + 1) * sizeof(int));
    int* bsum  = (int*)alloc((size_t)SCAN_NCH * sizeof(int));
    int4* elist = (int4*)alloc((size_t)NNZ_ * sizeof(int4));
    int2* vlist = (int2*)alloc((size_t)NNZ_ * sizeof(int2));
    int2* slist = (int2*)alloc((size_t)SNNZ_ * sizeof(int2));

    // ---- build CSR (hist+wconv fused; scanB folded into scanC; packed place) ----
    hipMemsetAsync(cnt, 0, (size_t)SCAN_TOT * sizeof(int), stream);
    hist_wconv_kernel<<<NNZ_ / 256, 256, 0, stream>>>(inc_rows, inc_cols, sent_cols, cnt,
                                                      W1, W2, Wt1h, Wt1l, Wt2h, Wt2l);
    scanA_kernel<<<SCAN_NCH, 256, 0, stream>>>(cnt, bsum);
    scanC_kernel<<<SCAN_NCH, 256, 0, stream>>>(cnt, bsum, rowptr_e, rowptr_v, rowptr_s, fill);
    place_kernel<<<NNZ_ / 256, 256, 0, stream>>>(inc_rows, inc_cols, inc_vals,
                                                 sent_rows, sent_cols, sent_vals,
                                                 x, deg_e, deg_v, fill,
                                                 elist, vlist, slist);

    // ---- EW = emb @ W1 (bf16 out) + EA = emb @ attW0 (free, f32) ----
    gemm_mfma_kernel<true, false, false><<<(VOCAB_ + 63) / 64, 256, 0, stream>>>(
        emb, VOCAB_, D_, D_, Wt1h, Wt1l, 320, nullptr, EW,
        attW0, EA, nullptr, nullptr, nullptr, nullptr);

    // ---- pool layer 0 (fused softmax+partial; logits from EA) ----
    {
        dim3 pg(B_, PCHUNK);
        pool_partial_kernel<true><<<pg, 256, 0, stream>>>(emb, D_, D_, x, EA,
                                                          tf_idf, attW0 + D_, attb0,
                                                          ps0, pm0);
    }

    // ---- layer 1 sparse chain @ dim 256 (deg folded into vals) ----
    gather256_kernel<2, false, false><<<NE_ / 4, 256, 0, stream>>>(
        rowptr_e, elist, EW, nullptr, m, NE_, nullptr, nullptr, nullptr, nullptr);
    gather256_kernel<0, false, false><<<NE_ / 4, 256, 0, stream>>>(
        rowptr_s, slist, m, nullptr, m2, NE_, nullptr, nullptr, nullptr, nullptr);
    gather256_kernel<0, true, true><<<NV_ / 4, 256, 0, stream>>>(
        rowptr_v, vlist, m2, b1, h1, NV_, attW1, attb1, tf_idf, e);

    // ---- pool layer 1 ----
    {
        dim3 pg(B_, PCHUNK);
        pool_partial_kernel<false><<<pg, 256, 0, stream>>>(h1, HID_, HID_, nullptr, e,
                                                           nullptr, nullptr, nullptr,
                                                           ps1, pm1);
    }

    // ---- layer 2: e-gather, s-gather, W2 hoisted to edge level (8192-row GEMM), v-gather
    gather256_kernel<1, false, false><<<NE_ / 4, 256, 0, stream>>>(
        rowptr_e, elist, h1, nullptr, m, NE_, nullptr, nullptr, nullptr, nullptr);
    gather256_kernel<0, false, false><<<NE_ / 4, 256, 0, stream>>>(
        rowptr_s, slist, m, nullptr, m2, NE_, nullptr, nullptr, nullptr, nullptr);
    // MW = m2 @ W2  (H(m2@W2) == (H m2)@W2; deg_v folded in vlist)
    gemm_mfma_kernel<false, false, false><<<NE_ / 64, 256, 0, stream>>>(
        m2, NE_, HID_, HID_, Wt2h, Wt2l, 256, nullptr, MW,
        nullptr, nullptr, nullptr, nullptr, nullptr, nullptr);
    // h2 = relu(gather(MW) + b2) + e2 logits in epilogue
    gather256_kernel<0, true, true><<<NV_ / 4, 256, 0, stream>>>(
        rowptr_v, vlist, MW, b2, h2, NV_, attW2, attb2, tf_idf, e);

    // ---- pool layer 2 ----
    {
        dim3 pg(B_, PCHUNK);
        pool_partial_kernel<false><<<pg, 256, 0, stream>>>(h2, HID_, HID_, nullptr, e,
                                                           nullptr, nullptr, nullptr,
                                                           ps2, pm2);
    }

    // ---- final (fused combine + GEMV) ----
    final_kernel<<<B_, 256, 0, stream>>>(ps0, pm0, ps1, pm1, ps2, pm2,
                                         pW0, pb0, pW1, pb1, pW2, pb2, out);
}

// Round 16
// 313.171 us; speedup vs baseline: 5.1557x; 1.0307x over previous
//
#include <hip/hip_runtime.h>
#include <cstddef>

#define B_   64
#define N_   512
#define NV_  32768
#define NE_  8192
#define NNZ_ 262144
#define SNNZ_ 24576
#define D_   300
#define HID_ 256
#define NC_  10
#define VOCAB_ 30000
#define PCHUNK 8
#define PVN (N_ / PCHUNK)   // 64 nodes per pool chunk
#define POOL_BLOCKS (B_ * PCHUNK)       // 512
#define EGATHER_BLOCKS (NE_ / 4)        // 2048

#define SCAN_TOT (NE_ + NV_ + NE_)      // 49152 counts, contiguous [cnt_e|cnt_v|cnt_s]
#define SCAN_NCH (SCAN_TOT / 1024)      // 48 chunks
#define SEG1_CH  (NE_ / 1024)           // 8  (start of cnt_v chunks)
#define SEG2_CH  ((NE_ + NV_) / 1024)   // 40 (start of cnt_s chunks)
#define WCONV_TOT (256 * 320 + 256 * 256)

using u16 = unsigned short;
typedef __attribute__((ext_vector_type(8))) short short8;
typedef __attribute__((ext_vector_type(4))) float f32x4;

__device__ __forceinline__ float bf2f(u16 v) {
    union { unsigned int u; float f; } uf;
    uf.u = ((unsigned int)v) << 16;
    return uf.f;
}
__device__ __forceinline__ u16 f2bf(float f) {
    union { float f; unsigned int u; } uf; uf.f = f;
    unsigned int u = uf.u;
    unsigned int r = u + 0x7fffu + ((u >> 16) & 1u);
    return (u16)(r >> 16);
}

// ---------------- CSR build + weight conversion -------------------------------------
__global__ __launch_bounds__(256) void hist_wconv_kernel(const int* __restrict__ inc_rows,
                                                         const int* __restrict__ inc_cols,
                                                         const int* __restrict__ sent_cols,
                                                         int* __restrict__ cnt,
                                                         const float* __restrict__ W1,
                                                         const float* __restrict__ W2,
                                                         u16* __restrict__ Wt1h,
                                                         u16* __restrict__ Wt1l,
                                                         u16* __restrict__ Wt2h,
                                                         u16* __restrict__ Wt2l) {
    int i = blockIdx.x * 256 + threadIdx.x;
    atomicAdd(&cnt[inc_cols[i]], 1);
    atomicAdd(&cnt[NE_ + inc_rows[i]], 1);
    if (i < SNNZ_) atomicAdd(&cnt[NE_ + NV_ + sent_cols[i]], 1);
    if (i < WCONV_TOT) {
        int id = i;
        const float* W; u16 *Wh, *Wl; int K, KP;
        if (id < 256 * 320) { W = W1; Wh = Wt1h; Wl = Wt1l; K = D_; KP = 320; }
        else { id -= 256 * 320; W = W2; Wh = Wt2h; Wl = Wt2l; K = HID_; KP = 256; }
        int n = id & 255, k = id >> 8;
        float v = (k < K) ? W[(size_t)k * HID_ + n] : 0.f;
        u16 hi = f2bf(v);
        Wh[(size_t)n * KP + k] = hi;
        Wl[(size_t)n * KP + k] = f2bf(v - bf2f(hi));
    }
}

__global__ __launch_bounds__(256) void scanA_kernel(const int* __restrict__ cnt,
                                                    int* __restrict__ bsum) {
    int blk = blockIdx.x, t = threadIdx.x;
    int4 v = reinterpret_cast<const int4*>(cnt)[blk * 256 + t];
    int s = v.x + v.y + v.z + v.w;
    __shared__ int red[256];
    red[t] = s;
    __syncthreads();
    for (int o = 128; o > 0; o >>= 1) {
        if (t < o) red[t] += red[t + o];
        __syncthreads();
    }
    if (t == 0) bsum[blk] = red[0];
}

__global__ __launch_bounds__(256) void scanC_kernel(const int* __restrict__ cnt,
                                                    const int* __restrict__ bsum,
                                                    int* __restrict__ rowptr_e,
                                                    int* __restrict__ rowptr_v,
                                                    int* __restrict__ rowptr_s,
                                                    int* __restrict__ fill) {
    int blk = blockIdx.x, t = threadIdx.x;
    int segstart = (blk < SEG1_CH) ? 0 : ((blk < SEG2_CH) ? SEG1_CH : SEG2_CH);
    int cbase = 0;
    for (int c = segstart; c < blk; ++c) cbase += bsum[c];
    int gi = blk * 1024 + t * 4;
    int4 v = reinterpret_cast<const int4*>(cnt)[blk * 256 + t];
    int s0 = v.x, s1 = s0 + v.y, s2 = s1 + v.z, s3 = s2 + v.w;
    __shared__ int part[256];
    part[t] = s3;
    __syncthreads();
    for (int o = 1; o < 256; o <<= 1) {
        int a = (t >= o) ? part[t - o] : 0;
        __syncthreads();
        part[t] += a;
        __syncthreads();
    }
    int excl = (t > 0 ? part[t - 1] : 0) + cbase;
    int4 e;
    e.x = excl; e.y = excl + s0; e.z = excl + s1; e.w = excl + s2;
    int* rp; int li;
    if (blk < SEG1_CH)      { rp = rowptr_e; li = gi; }
    else if (blk < SEG2_CH) { rp = rowptr_v; li = gi - NE_; }
    else                    { rp = rowptr_s; li = gi - NE_ - NV_; }
    rp[li + 0] = e.x; rp[li + 1] = e.y; rp[li + 2] = e.z; rp[li + 3] = e.w;
    reinterpret_cast<int4*>(fill)[blk * 256 + t] = e;
    if (t == 255) {
        int tot = excl + s3;
        if (blk == SEG1_CH - 1) rowptr_e[NE_] = tot;
        if (blk == SEG2_CH - 1) rowptr_v[NV_] = tot;
        if (blk == SCAN_NCH - 1) rowptr_s[NE_] = tot;
    }
}

__global__ __launch_bounds__(256) void place_kernel(const int* __restrict__ inc_rows,
                                                    const int* __restrict__ inc_cols,
                                                    const float* __restrict__ inc_vals,
                                                    const int* __restrict__ sent_rows,
                                                    const int* __restrict__ sent_cols,
                                                    const float* __restrict__ sent_vals,
                                                    const int* __restrict__ x,
                                                    const float* __restrict__ deg_e,
                                                    const float* __restrict__ deg_v,
                                                    int* __restrict__ fill,
                                                    int4* __restrict__ elist,
                                                    int2* __restrict__ vlist,
                                                    int2* __restrict__ slist) {
    int i = blockIdx.x * 256 + threadIdx.x;
    int r = inc_rows[i], c = inc_cols[i];
    float v = inc_vals[i];
    int pe = atomicAdd(&fill[c], 1);
    int4 ee;
    ee.x = r; ee.y = x[r];
    ee.z = __float_as_int(v * deg_e[c]); ee.w = 0;
    elist[pe] = ee;
    int pv = atomicAdd(&fill[NE_ + r], 1);
    int2 vv;
    vv.x = c; vv.y = __float_as_int(v * deg_v[r]);
    vlist[pv] = vv;
    if (i < SNNZ_) {
        int ps = atomicAdd(&fill[NE_ + NV_ + sent_cols[i]], 1);
        int2 ss;
        ss.x = sent_rows[i]; ss.y = __float_as_int(sent_vals[i]);
        slist[ps] = ss;
    }
}

// ---------------- per-wave 256-dim gather helpers -----------------------------------
template <int MODE>
__device__ __forceinline__ float4 seg_gather(const int* __restrict__ rowptr,
                                             const void* __restrict__ listv,
                                             const u16* __restrict__ src,
                                             int seg, int lane) {
    int start = rowptr[seg], end = rowptr[seg + 1];
    float4 acc = make_float4(0.f, 0.f, 0.f, 0.f);
    for (int k = start; k < end; ++k) {
        int r; float v;
        if constexpr (MODE == 0) {
            int2 q = ((const int2*)listv)[k];
            r = q.x; v = __int_as_float(q.y);
        } else {
            int4 q = ((const int4*)listv)[k];
            r = (MODE == 1) ? q.x : q.y;
            v = __int_as_float(q.z);
        }
        ushort4 sv = *reinterpret_cast<const ushort4*>(src + (size_t)r * 256 + lane * 4);
        acc.x += v * bf2f(sv.x); acc.y += v * bf2f(sv.y);
        acc.z += v * bf2f(sv.z); acc.w += v * bf2f(sv.w);
    }
    return acc;
}
__device__ __forceinline__ void store_bf4(u16* dst, int seg, int lane, float4 o) {
    ushort4 o4;
    o4.x = f2bf(o.x); o4.y = f2bf(o.y); o4.z = f2bf(o.z); o4.w = f2bf(o.w);
    *reinterpret_cast<ushort4*>(dst + (size_t)seg * 256 + lane * 4) = o4;
}

// ---------------- 256-dim segment gather-sum kernel (standalone) --------------------
template <int MODE, bool EPI, bool ATT>
__global__ __launch_bounds__(256) void gather256_kernel(const int* __restrict__ rowptr,
                                                        const void* __restrict__ listv,
                                                        const u16* __restrict__ src,
                                                        const float* __restrict__ bias,
                                                        u16* __restrict__ dst, int nseg,
                                                        const float* __restrict__ attW,
                                                        const float* __restrict__ attb,
                                                        const float* __restrict__ tfidf,
                                                        float* __restrict__ e) {
    int seg = (blockIdx.x * 256 + threadIdx.x) >> 6;
    int lane = threadIdx.x & 63;
    if (seg >= nseg) return;
    float4 o = seg_gather<MODE>(rowptr, listv, src, seg, lane);
    if constexpr (EPI) {
        float4 bv = reinterpret_cast<const float4*>(bias)[lane];
        o.x = fmaxf(o.x + bv.x, 0.f); o.y = fmaxf(o.y + bv.y, 0.f);
        o.z = fmaxf(o.z + bv.z, 0.f); o.w = fmaxf(o.w + bv.w, 0.f);
    }
    store_bf4(dst, seg, lane, o);
    if constexpr (ATT) {
        float4 aw = reinterpret_cast<const float4*>(attW)[lane];
        float pe = o.x * aw.x + o.y * aw.y + o.z * aw.z + o.w * aw.w;
#pragma unroll
        for (int off = 32; off > 0; off >>= 1) pe += __shfl_down(pe, off);
        if (lane == 0)
            e[seg] = pe + tfidf[seg * 2] * attW[HID_] + tfidf[seg * 2 + 1] * attW[HID_ + 1]
                     + attb[0];
    }
}

// ---------------- MFMA GEMM, full-N tile 64x256: C = A @ Wt^T -----------------------
template <bool SPLIT_A, bool EPI, bool ATT>
__global__ __launch_bounds__(256) void gemm_mfma_kernel(const void* __restrict__ Av,
                                                        int M, int K, int Ks,
                                                        const u16* __restrict__ Bth,
                                                        const u16* __restrict__ Btl, int bstride,
                                                        const float* __restrict__ bias,
                                                        void* __restrict__ Cv,
                                                        const float* __restrict__ attWA,
                                                        float* __restrict__ EAp,
                                                        const float* __restrict__ attW,
                                                        const float* __restrict__ attb,
                                                        const float* __restrict__ tfidf,
                                                        float* __restrict__ e) {
    __shared__ __align__(16) u16 Ah[64 * 32];
    __shared__ __align__(16) u16 Al[64 * 32];
    __shared__ __align__(16) u16 Bh[256 * 32];
    __shared__ __align__(16) u16 Bl[256 * 32];
    int tid = threadIdx.x;
    int bm0 = blockIdx.x * 64;
    int w = tid >> 6, l = tid & 63;
    int srow = tid >> 2;
    int skbp = tid & 3;
    int skbl = skbp ^ ((srow >> 1) & 3);
    int arow = bm0 + srow; if (arow >= M) arow = M - 1;
    int sdst = srow * 32 + skbp * 8;
    int frow = w * 16 + (l & 15);
    int akbp = (l >> 4) ^ ((frow >> 1) & 3);

    f32x4 acc[16] = {};
    float ea = 0.f;
    int nkt = (K + 31) / 32;
    for (int kt = 0; kt < nkt; ++kt) {
        if (kt) __syncthreads();
        int kbase = kt * 32 + skbl * 8;
        if constexpr (SPLIT_A) {
            const float* Arow = (const float*)Av + (size_t)arow * Ks;
            float av[8];
            if (kbase + 8 <= K) {
                float4 v0 = *reinterpret_cast<const float4*>(Arow + kbase);
                float4 v1 = *reinterpret_cast<const float4*>(Arow + kbase + 4);
                av[0] = v0.x; av[1] = v0.y; av[2] = v0.z; av[3] = v0.w;
                av[4] = v1.x; av[5] = v1.y; av[6] = v1.z; av[7] = v1.w;
            } else {
#pragma unroll
                for (int ee = 0; ee < 8; ++ee) {
                    int kk = kbase + ee;
                    av[ee] = (kk < K) ? Arow[kk] : 0.f;
                }
            }
            if (EAp) {
#pragma unroll
                for (int ee = 0; ee < 8; ++ee) {
                    int kk = kbase + ee;
                    ea += av[ee] * ((kk < K) ? attWA[kk] : 0.f);
                }
            }
            short8 h8, l8;
#pragma unroll
            for (int ee = 0; ee < 8; ++ee) {
                u16 hi = f2bf(av[ee]);
                h8[ee] = (short)hi;
                l8[ee] = (short)f2bf(av[ee] - bf2f(hi));
            }
            *(short8*)&Ah[sdst] = h8;
            *(short8*)&Al[sdst] = l8;
        } else {
            const u16* Arow = (const u16*)Av + (size_t)arow * Ks;
            *(short8*)&Ah[sdst] = *(const short8*)(Arow + kbase);
        }
#pragma unroll
        for (int i = 0; i < 4; ++i) {
            int br = i * 64 + srow;
            int bkl = skbp ^ ((br >> 1) & 3);
            *(short8*)&Bh[br * 32 + skbp * 8] =
                *(const short8*)(Bth + (size_t)br * bstride + kt * 32 + bkl * 8);
            *(short8*)&Bl[br * 32 + skbp * 8] =
                *(const short8*)(Btl + (size_t)br * bstride + kt * 32 + bkl * 8);
        }
        __syncthreads();
        short8 ah = *(const short8*)&Ah[frow * 32 + akbp * 8];
        short8 al;
        if constexpr (SPLIT_A) al = *(const short8*)&Al[frow * 32 + akbp * 8];
#pragma unroll
        for (int nt = 0; nt < 16; ++nt) {
            int nrow = nt * 16 + (l & 15);
            int bkbp = (l >> 4) ^ ((nrow >> 1) & 3);
            short8 tbh = *(const short8*)&Bh[nrow * 32 + bkbp * 8];
            short8 tbl = *(const short8*)&Bl[nrow * 32 + bkbp * 8];
            acc[nt] = __builtin_amdgcn_mfma_f32_16x16x32_bf16(ah, tbh, acc[nt], 0, 0, 0);
            if constexpr (SPLIT_A)
                acc[nt] = __builtin_amdgcn_mfma_f32_16x16x32_bf16(al, tbh, acc[nt], 0, 0, 0);
            acc[nt] = __builtin_amdgcn_mfma_f32_16x16x32_bf16(ah, tbl, acc[nt], 0, 0, 0);
        }
    }
    if constexpr (SPLIT_A) {
        if (EAp) {
            ea += __shfl_xor(ea, 1);
            ea += __shfl_xor(ea, 2);
            if ((tid & 3) == 0 && bm0 + srow < M) EAp[bm0 + srow] = ea;
        }
    }
#pragma unroll
    for (int r = 0; r < 4; ++r) {
        int row = bm0 + w * 16 + (l >> 4) * 4 + r;
        if (row >= M) continue;
        float er = 0.f;
#pragma unroll
        for (int nt = 0; nt < 16; ++nt) {
            int col = nt * 16 + (l & 15);
            float v = acc[nt][r];
            if constexpr (EPI) {
                v = v + bias[col];
                v = v > 0.f ? v : 0.f;
            }
            if constexpr (ATT) er += v * attW[col];
            ((u16*)Cv)[(size_t)row * 256 + col] = f2bf(v);
        }
        if constexpr (ATT) {
            er += __shfl_xor(er, 1);
            er += __shfl_xor(er, 2);
            er += __shfl_xor(er, 4);
            er += __shfl_xor(er, 8);
            if ((l & 15) == 0)
                e[row] = er + tfidf[row * 2] * attW[HID_] + tfidf[row * 2 + 1] * attW[HID_ + 1]
                         + attb[0];
        }
    }
}

// ---------------- pool partial body (device fn, callable from fused kernels) --------
template <bool L0>
__device__ __forceinline__ void pool_body(int b, int c,
                                          const void* __restrict__ h, int dim, int stride,
                                          const int* __restrict__ x,
                                          const float* __restrict__ EA_or_e,
                                          const float* __restrict__ tfidf,
                                          const float* __restrict__ attWtail,
                                          const float* __restrict__ attb,
                                          float* __restrict__ psum,
                                          float* __restrict__ pmax) {
    int t = threadIdx.x;
    __shared__ float sev[N_];
    __shared__ int srows[N_];
    __shared__ float red[256];
    __shared__ float wv[PVN];
    int n0 = b * N_ + t, n1 = n0 + 256;
    float ev0, ev1;
    int r0, r1;
    if constexpr (L0) {
        r0 = x[n0]; r1 = x[n1];
        float a0 = attWtail[0], a1 = attWtail[1], ab = attb[0];
        ev0 = EA_or_e[r0] + tfidf[n0 * 2] * a0 + tfidf[n0 * 2 + 1] * a1 + ab;
        ev1 = EA_or_e[r1] + tfidf[n1 * 2] * a0 + tfidf[n1 * 2 + 1] * a1 + ab;
    } else {
        r0 = n0; r1 = n1;
        ev0 = EA_or_e[n0]; ev1 = EA_or_e[n1];
    }
    sev[t] = ev0; sev[t + 256] = ev1;
    srows[t] = r0; srows[t + 256] = r1;
    red[t] = fmaxf(ev0, ev1);
    __syncthreads();
    for (int s = 128; s > 0; s >>= 1) {
        if (t < s) red[t] = fmaxf(red[t], red[t + s]);
        __syncthreads();
    }
    float mx = red[0];
    __syncthreads();
    red[t] = expf(ev0 - mx) + expf(ev1 - mx);
    __syncthreads();
    for (int s = 128; s > 0; s >>= 1) {
        if (t < s) red[t] += red[t + s];
        __syncthreads();
    }
    float inv = 1.f / (red[0] + 1e-10f);
    if (t < PVN) wv[t] = expf(sev[c * PVN + t] - mx) * inv;
    __syncthreads();
    float s0 = 0.f, s1 = 0.f, m0 = -3.4e38f, m1 = -3.4e38f;
    int d0 = t, d1 = t + 256;
    bool has1 = d1 < dim;
    for (int i = 0; i < PVN; ++i) {
        int row = srows[c * PVN + i];
        float ww = wv[i];
        float x0, x1 = 0.f;
        if constexpr (L0) {
            const float* hp = (const float*)h + (size_t)row * stride;
            x0 = hp[d0];
            if (has1) x1 = hp[d1];
        } else {
            const u16* hp = (const u16*)h + (size_t)row * stride;
            x0 = bf2f(hp[d0]);
            if (has1) x1 = bf2f(hp[d1]);
        }
        s0 += ww * x0;
        m0 = fmaxf(m0, x0);
        if (has1) {
            s1 += ww * x1;
            m1 = fmaxf(m1, x1);
        }
    }
    size_t base = ((size_t)b * PCHUNK + c) * dim;
    psum[base + d0] = s0;
    pmax[base + d0] = m0;
    if (has1) {
        psum[base + d1] = s1;
        pmax[base + d1] = m1;
    }
}

// ---------------- standalone pool kernel (layer 2) ----------------------------------
template <bool L0>
__global__ __launch_bounds__(256) void pool_partial_kernel(const void* __restrict__ h, int dim,
                                                           int stride,
                                                           const int* __restrict__ x,
                                                           const float* __restrict__ EA_or_e,
                                                           const float* __restrict__ tfidf,
                                                           const float* __restrict__ attWtail,
                                                           const float* __restrict__ attb,
                                                           float* __restrict__ psum,
                                                           float* __restrict__ pmax) {
    pool_body<L0>(blockIdx.x, blockIdx.y, h, dim, stride, x, EA_or_e,
                  tfidf, attWtail, attb, psum, pmax);
}

// ---------------- fused: pool partial (blocks 0..511) || e-gather (rest) ------------
// The two parts are data-independent; pure grid concatenation, no cross-block sync.
template <bool L0, int EMODE>
__global__ __launch_bounds__(256) void pool_gather_kernel(const void* __restrict__ h, int dim,
                                                          int stride,
                                                          const int* __restrict__ x,
                                                          const float* __restrict__ EA_or_e,
                                                          const float* __restrict__ tfidf,
                                                          const float* __restrict__ attWtail,
                                                          const float* __restrict__ attb,
                                                          float* __restrict__ psum,
                                                          float* __restrict__ pmax,
                                                          const int* __restrict__ rowptr,
                                                          const void* __restrict__ listv,
                                                          const u16* __restrict__ src,
                                                          u16* __restrict__ dst) {
    if (blockIdx.x < POOL_BLOCKS) {
        pool_body<L0>(blockIdx.x >> 3, blockIdx.x & 7, h, dim, stride, x, EA_or_e,
                      tfidf, attWtail, attb, psum, pmax);
    } else {
        int blk = blockIdx.x - POOL_BLOCKS;
        int seg = (blk * 256 + threadIdx.x) >> 6;
        int lane = threadIdx.x & 63;
        if (seg < NE_)
            store_bf4(dst, seg, lane, seg_gather<EMODE>(rowptr, listv, src, seg, lane));
    }
}

// ---------------- final: combine chunk partials on the fly + GEMV -------------------
__global__ __launch_bounds__(256) void final_kernel(const float* __restrict__ ps0,
                                                    const float* __restrict__ pm0,
                                                    const float* __restrict__ ps1,
                                                    const float* __restrict__ pm1,
                                                    const float* __restrict__ ps2,
                                                    const float* __restrict__ pm2,
                                                    const float* __restrict__ pW0,
                                                    const float* __restrict__ pb0,
                                                    const float* __restrict__ pW1,
                                                    const float* __restrict__ pb1,
                                                    const float* __restrict__ pW2,
                                                    const float* __restrict__ pb2,
                                                    float* __restrict__ out) {
    int b = blockIdx.x;
    int t = threadIdx.x;
    int lane = t & 63, wv = t >> 6;
    float acc[NC_] = {};
    for (int k = t; k < 2 * D_; k += 256) {
        float pv;
        if (k < D_) {
            pv = 0.f;
#pragma unroll
            for (int c = 0; c < PCHUNK; ++c) pv += ps0[((size_t)b * PCHUNK + c) * D_ + k];
        } else {
            pv = -3.4e38f;
#pragma unroll
            for (int c = 0; c < PCHUNK; ++c)
                pv = fmaxf(pv, pm0[((size_t)b * PCHUNK + c) * D_ + (k - D_)]);
        }
        const float* wp = pW0 + (size_t)k * NC_;
#pragma unroll
        for (int c = 0; c < NC_; ++c) acc[c] += pv * wp[c];
    }
    for (int k = t; k < 2 * HID_; k += 256) {
        float pv;
        if (k < HID_) {
            pv = 0.f;
#pragma unroll
            for (int c = 0; c < PCHUNK; ++c) pv += ps1[((size_t)b * PCHUNK + c) * HID_ + k];
        } else {
            pv = -3.4e38f;
#pragma unroll
            for (int c = 0; c < PCHUNK; ++c)
                pv = fmaxf(pv, pm1[((size_t)b * PCHUNK + c) * HID_ + (k - HID_)]);
        }
        const float* wp = pW1 + (size_t)k * NC_;
#pragma unroll
        for (int c = 0; c < NC_; ++c) acc[c] += pv * wp[c];
    }
    for (int k = t; k < 2 * HID_; k += 256) {
        float pv;
        if (k < HID_) {
            pv = 0.f;
#pragma unroll
            for (int c = 0; c < PCHUNK; ++c) pv += ps2[((size_t)b * PCHUNK + c) * HID_ + k];
        } else {
            pv = -3.4e38f;
#pragma unroll
            for (int c = 0; c < PCHUNK; ++c)
                pv = fmaxf(pv, pm2[((size_t)b * PCHUNK + c) * HID_ + (k - HID_)]);
        }
        const float* wp = pW2 + (size_t)k * NC_;
#pragma unroll
        for (int c = 0; c < NC_; ++c) acc[c] += pv * wp[c];
    }
    __shared__ float red[4][NC_];
#pragma unroll
    for (int c = 0; c < NC_; ++c) {
        float s = acc[c];
#pragma unroll
        for (int off = 32; off > 0; off >>= 1) s += __shfl_down(s, off);
        if (lane == 0) red[wv][c] = s;
    }
    __syncthreads();
    if (t < NC_) {
        float s = red[0][t] + red[1][t] + red[2][t] + red[3][t];
        out[b * NC_ + t] = s + pb0[t] + pb1[t] + pb2[t];
    }
}

extern "C" void kernel_launch(void* const* d_in, const int* in_sizes, int n_in,
                              void* d_out, int out_size, void* d_ws, size_t ws_size,
                              hipStream_t stream) {
    const int*   x         = (const int*)d_in[0];
    const int*   inc_rows  = (const int*)d_in[1];
    const int*   inc_cols  = (const int*)d_in[2];
    const float* inc_vals  = (const float*)d_in[3];
    const int*   sent_rows = (const int*)d_in[4];
    const int*   sent_cols = (const int*)d_in[5];
    const float* sent_vals = (const float*)d_in[6];
    const float* deg_v     = (const float*)d_in[7];
    const float* deg_e     = (const float*)d_in[8];
    const float* tf_idf = (const float*)d_in[11];
    const float* emb    = (const float*)d_in[12];
    const float* W1 = (const float*)d_in[13];
    const float* b1 = (const float*)d_in[14];
    const float* W2 = (const float*)d_in[15];
    const float* b2 = (const float*)d_in[16];
    const float* attW0 = (const float*)d_in[17];
    const float* attb0 = (const float*)d_in[18];
    const float* attW1 = (const float*)d_in[19];
    const float* attb1 = (const float*)d_in[20];
    const float* attW2 = (const float*)d_in[21];
    const float* attb2 = (const float*)d_in[22];
    const float* pW0 = (const float*)d_in[23];
    const float* pb0 = (const float*)d_in[24];
    const float* pW1 = (const float*)d_in[25];
    const float* pb1 = (const float*)d_in[26];
    const float* pW2 = (const float*)d_in[27];
    const float* pb2 = (const float*)d_in[28];
    float* out = (float*)d_out;

    // workspace layout
    char* ws = (char*)d_ws;
    size_t off = 0;
    auto alloc = [&](size_t bytes) {
        void* p = ws + off;
        off += (bytes + 255) & ~(size_t)255;
        return p;
    };
    u16* EW = (u16*)alloc((size_t)VOCAB_ * HID_ * sizeof(u16)); // emb @ W1, bf16
    u16* MW = (u16*)alloc((size_t)NE_ * HID_ * sizeof(u16));    // m2 @ W2, bf16
    u16* m  = (u16*)alloc((size_t)NE_ * HID_ * sizeof(u16));
    u16* m2 = (u16*)alloc((size_t)NE_ * HID_ * sizeof(u16));
    u16* h1 = (u16*)alloc((size_t)NV_ * HID_ * sizeof(u16));
    u16* h2 = (u16*)alloc((size_t)NV_ * HID_ * sizeof(u16));
    u16* Wt1h = (u16*)alloc((size_t)HID_ * 320 * sizeof(u16));
    u16* Wt1l = (u16*)alloc((size_t)HID_ * 320 * sizeof(u16));
    u16* Wt2h = (u16*)alloc((size_t)HID_ * 256 * sizeof(u16));
    u16* Wt2l = (u16*)alloc((size_t)HID_ * 256 * sizeof(u16));
    float* EA = (float*)alloc((size_t)VOCAB_ * sizeof(float));  // emb @ attW0[:300]
    float* e  = (float*)alloc((size_t)NV_ * sizeof(float));
    float* ps0 = (float*)alloc((size_t)B_ * PCHUNK * D_ * sizeof(float));
    float* pm0 = (float*)alloc((size_t)B_ * PCHUNK * D_ * sizeof(float));
    float* ps1 = (float*)alloc((size_t)B_ * PCHUNK * HID_ * sizeof(float));
    float* pm1 = (float*)alloc((size_t)B_ * PCHUNK * HID_ * sizeof(float));
    float* ps2 = (float*)alloc((size_t)B_ * PCHUNK * HID_ * sizeof(float));
    float* pm2 = (float*)alloc((size_t)B_ * PCHUNK * HID_ * sizeof(float));
    // CSR structures
    int* cnt  = (int*)alloc((size_t)SCAN_TOT * sizeof(int));  // [cnt_e|cnt_v|cnt_s]
    int* fill = (int*)alloc((size_t)SCAN_TOT * sizeof(int));
    int* rowptr_e = (int*)alloc((size_t)(NE_ + 1) * sizeof(int));
    int* rowptr_v = (int*)alloc((size_t)(NV_ + 1) * sizeof(int));
    int* rowptr_s = (int*)alloc((size_t)(NE_ + 1) * sizeof(int));
    int* bsum  = (int*)alloc((size_t)SCAN_NCH * sizeof(int));
    int4* elist = (int4*)alloc((size_t)NNZ_ * sizeof(int4));
    int2* vlist = (int2*)alloc((size_t)NNZ_ * sizeof(int2));
    int2* slist = (int2*)alloc((size_t)SNNZ_ * sizeof(int2));

    // ---- build CSR (hist+wconv fused; scanB folded into scanC; packed place) ----
    hipMemsetAsync(cnt, 0, (size_t)SCAN_TOT * sizeof(int), stream);
    hist_wconv_kernel<<<NNZ_ / 256, 256, 0, stream>>>(inc_rows, inc_cols, sent_cols, cnt,
                                                      W1, W2, Wt1h, Wt1l, Wt2h, Wt2l);
    scanA_kernel<<<SCAN_NCH, 256, 0, stream>>>(cnt, bsum);
    scanC_kernel<<<SCAN_NCH, 256, 0, stream>>>(cnt, bsum, rowptr_e, rowptr_v, rowptr_s, fill);
    place_kernel<<<NNZ_ / 256, 256, 0, stream>>>(inc_rows, inc_cols, inc_vals,
                                                 sent_rows, sent_cols, sent_vals,
                                                 x, deg_e, deg_v, fill,
                                                 elist, vlist, slist);

    // ---- EW = emb @ W1 (bf16 out) + EA = emb @ attW0 (free, f32) ----
    gemm_mfma_kernel<true, false, false><<<(VOCAB_ + 63) / 64, 256, 0, stream>>>(
        emb, VOCAB_, D_, D_, Wt1h, Wt1l, 320, nullptr, EW,
        attW0, EA, nullptr, nullptr, nullptr, nullptr);

    // ---- fused: pool layer 0 (logits from EA) || layer-1 e-gather ----
    pool_gather_kernel<true, 2><<<POOL_BLOCKS + EGATHER_BLOCKS, 256, 0, stream>>>(
        emb, D_, D_, x, EA, tf_idf, attW0 + D_, attb0, ps0, pm0,
        rowptr_e, elist, EW, m);

    // ---- layer 1: s-gather, v-gather (EPI+ATT) ----
    gather256_kernel<0, false, false><<<NE_ / 4, 256, 0, stream>>>(
        rowptr_s, slist, m, nullptr, m2, NE_, nullptr, nullptr, nullptr, nullptr);
    gather256_kernel<0, true, true><<<NV_ / 4, 256, 0, stream>>>(
        rowptr_v, vlist, m2, b1, h1, NV_, attW1, attb1, tf_idf, e);

    // ---- fused: pool layer 1 || layer-2 e-gather ----
    pool_gather_kernel<false, 1><<<POOL_BLOCKS + EGATHER_BLOCKS, 256, 0, stream>>>(
        h1, HID_, HID_, nullptr, e, nullptr, nullptr, nullptr, ps1, pm1,
        rowptr_e, elist, h1, m);

    // ---- layer 2: s-gather, W2 hoisted to edge level, v-gather ----
    gather256_kernel<0, false, false><<<NE_ / 4, 256, 0, stream>>>(
        rowptr_s, slist, m, nullptr, m2, NE_, nullptr, nullptr, nullptr, nullptr);
    gemm_mfma_kernel<false, false, false><<<NE_ / 64, 256, 0, stream>>>(
        m2, NE_, HID_, HID_, Wt2h, Wt2l, 256, nullptr, MW,
        nullptr, nullptr, nullptr, nullptr, nullptr, nullptr);
    gather256_kernel<0, true, true><<<NV_ / 4, 256, 0, stream>>>(
        rowptr_v, vlist, MW, b2, h2, NV_, attW2, attb2, tf_idf, e);

    // ---- pool layer 2 ----
    {
        dim3 pg(B_, PCHUNK);
        pool_partial_kernel<false><<<pg, 256, 0, stream>>>(h2, HID_, HID_, nullptr, e,
                                                           nullptr, nullptr, nullptr,
                                                           ps2, pm2);
    }

    // ---- final (fused combine + GEMV) ----
    final_kernel<<<B_, 256, 0, stream>>>(ps0, pm0, ps1, pm1, ps2, pm2,
                                         pW0, pb0, pW1, pb1, pW2, pb2, out);
}

// Round 17
// 254.204 us; speedup vs baseline: 6.3517x; 1.2320x over previous
//
#include <hip/hip_runtime.h>
#include <cstddef>

#define B_   64
#define N_   512
#define NV_  32768
#define NE_  8192
#define NNZ_ 262144
#define SNNZ_ 24576
#define D_   300
#define HID_ 256
#define NC_  10
#define VOCAB_ 30000
#define PCHUNK 8
#define PVN (N_ / PCHUNK)   // 64 nodes per pool chunk
#define POOL_BLOCKS (B_ * PCHUNK)       // 512
#define EGATHER_BLOCKS (NE_ / 4)        // 2048

#define SCAN_TOT (NE_ + NV_ + NE_)      // 49152 counts, contiguous [cnt_e|cnt_v|cnt_s]
#define SCAN_NCH (SCAN_TOT / 1024)      // 48 chunks
#define SEG1_CH  (NE_ / 1024)           // 8  (start of cnt_v chunks)
#define SEG2_CH  ((NE_ + NV_) / 1024)   // 40 (start of cnt_s chunks)
#define WCONV_TOT (256 * 320 + 256 * 256)

using u16 = unsigned short;
typedef __attribute__((ext_vector_type(8))) short short8;
typedef __attribute__((ext_vector_type(4))) float f32x4;

__device__ __forceinline__ float bf2f(u16 v) {
    union { unsigned int u; float f; } uf;
    uf.u = ((unsigned int)v) << 16;
    return uf.f;
}
__device__ __forceinline__ u16 f2bf(float f) {
    union { float f; unsigned int u; } uf; uf.f = f;
    unsigned int u = uf.u;
    unsigned int r = u + 0x7fffu + ((u >> 16) & 1u);
    return (u16)(r >> 16);
}

// ---------------- CSR build + weight conversion -------------------------------------
__global__ __launch_bounds__(256) void hist_wconv_kernel(const int* __restrict__ inc_rows,
                                                         const int* __restrict__ inc_cols,
                                                         const int* __restrict__ sent_cols,
                                                         int* __restrict__ cnt,
                                                         const float* __restrict__ W1,
                                                         const float* __restrict__ W2,
                                                         u16* __restrict__ Wt1h,
                                                         u16* __restrict__ Wt1l,
                                                         u16* __restrict__ Wt2h,
                                                         u16* __restrict__ Wt2l) {
    int i = blockIdx.x * 256 + threadIdx.x;
    atomicAdd(&cnt[inc_cols[i]], 1);
    atomicAdd(&cnt[NE_ + inc_rows[i]], 1);
    if (i < SNNZ_) atomicAdd(&cnt[NE_ + NV_ + sent_cols[i]], 1);
    if (i < WCONV_TOT) {
        int id = i;
        const float* W; u16 *Wh, *Wl; int K, KP;
        if (id < 256 * 320) { W = W1; Wh = Wt1h; Wl = Wt1l; K = D_; KP = 320; }
        else { id -= 256 * 320; W = W2; Wh = Wt2h; Wl = Wt2l; K = HID_; KP = 256; }
        int n = id & 255, k = id >> 8;
        float v = (k < K) ? W[(size_t)k * HID_ + n] : 0.f;
        u16 hi = f2bf(v);
        Wh[(size_t)n * KP + k] = hi;
        Wl[(size_t)n * KP + k] = f2bf(v - bf2f(hi));
    }
}

__global__ __launch_bounds__(256) void scanA_kernel(const int* __restrict__ cnt,
                                                    int* __restrict__ bsum) {
    int blk = blockIdx.x, t = threadIdx.x;
    int4 v = reinterpret_cast<const int4*>(cnt)[blk * 256 + t];
    int s = v.x + v.y + v.z + v.w;
    __shared__ int red[256];
    red[t] = s;
    __syncthreads();
    for (int o = 128; o > 0; o >>= 1) {
        if (t < o) red[t] += red[t + o];
        __syncthreads();
    }
    if (t == 0) bsum[blk] = red[0];
}

__global__ __launch_bounds__(256) void scanC_kernel(const int* __restrict__ cnt,
                                                    const int* __restrict__ bsum,
                                                    int* __restrict__ rowptr_e,
                                                    int* __restrict__ rowptr_v,
                                                    int* __restrict__ rowptr_s,
                                                    int* __restrict__ fill) {
    int blk = blockIdx.x, t = threadIdx.x;
    int segstart = (blk < SEG1_CH) ? 0 : ((blk < SEG2_CH) ? SEG1_CH : SEG2_CH);
    int cbase = 0;
    for (int c = segstart; c < blk; ++c) cbase += bsum[c];
    int gi = blk * 1024 + t * 4;
    int4 v = reinterpret_cast<const int4*>(cnt)[blk * 256 + t];
    int s0 = v.x, s1 = s0 + v.y, s2 = s1 + v.z, s3 = s2 + v.w;
    __shared__ int part[256];
    part[t] = s3;
    __syncthreads();
    for (int o = 1; o < 256; o <<= 1) {
        int a = (t >= o) ? part[t - o] : 0;
        __syncthreads();
        part[t] += a;
        __syncthreads();
    }
    int excl = (t > 0 ? part[t - 1] : 0) + cbase;
    int4 e;
    e.x = excl; e.y = excl + s0; e.z = excl + s1; e.w = excl + s2;
    int* rp; int li;
    if (blk < SEG1_CH)      { rp = rowptr_e; li = gi; }
    else if (blk < SEG2_CH) { rp = rowptr_v; li = gi - NE_; }
    else                    { rp = rowptr_s; li = gi - NE_ - NV_; }
    rp[li + 0] = e.x; rp[li + 1] = e.y; rp[li + 2] = e.z; rp[li + 3] = e.w;
    reinterpret_cast<int4*>(fill)[blk * 256 + t] = e;
    if (t == 255) {
        int tot = excl + s3;
        if (blk == SEG1_CH - 1) rowptr_e[NE_] = tot;
        if (blk == SEG2_CH - 1) rowptr_v[NV_] = tot;
        if (blk == SCAN_NCH - 1) rowptr_s[NE_] = tot;
    }
}

__global__ __launch_bounds__(256) void place_kernel(const int* __restrict__ inc_rows,
                                                    const int* __restrict__ inc_cols,
                                                    const float* __restrict__ inc_vals,
                                                    const int* __restrict__ sent_rows,
                                                    const int* __restrict__ sent_cols,
                                                    const float* __restrict__ sent_vals,
                                                    const int* __restrict__ x,
                                                    const float* __restrict__ deg_e,
                                                    const float* __restrict__ deg_v,
                                                    int* __restrict__ fill,
                                                    int4* __restrict__ elist,
                                                    int2* __restrict__ vlist,
                                                    int2* __restrict__ slist) {
    int i = blockIdx.x * 256 + threadIdx.x;
    int r = inc_rows[i], c = inc_cols[i];
    float v = inc_vals[i];
    int pe = atomicAdd(&fill[c], 1);
    int4 ee;
    ee.x = r; ee.y = x[r];
    ee.z = __float_as_int(v * deg_e[c]); ee.w = 0;
    elist[pe] = ee;
    int pv = atomicAdd(&fill[NE_ + r], 1);
    int2 vv;
    vv.x = c; vv.y = __float_as_int(v * deg_v[r]);
    vlist[pv] = vv;
    if (i < SNNZ_) {
        int ps = atomicAdd(&fill[NE_ + NV_ + sent_cols[i]], 1);
        int2 ss;
        ss.x = sent_rows[i]; ss.y = __float_as_int(sent_vals[i]);
        slist[ps] = ss;
    }
}

// ---------------- per-wave 256-dim gather helpers (4-way pipelined) -----------------
template <int MODE>
__device__ __forceinline__ float4 seg_gather(const int* __restrict__ rowptr,
                                             const void* __restrict__ listv,
                                             const u16* __restrict__ src,
                                             int seg, int lane) {
    int start = rowptr[seg], end = rowptr[seg + 1];
    float4 acc = make_float4(0.f, 0.f, 0.f, 0.f);
    int k = start;
    // 4-way batched: load 4 entries, issue 4 independent row loads, accumulate in order
    for (; k + 4 <= end; k += 4) {
        int r[4]; float v[4];
#pragma unroll
        for (int j = 0; j < 4; ++j) {
            if constexpr (MODE == 0) {
                int2 q = ((const int2*)listv)[k + j];
                r[j] = q.x; v[j] = __int_as_float(q.y);
            } else {
                int4 q = ((const int4*)listv)[k + j];
                r[j] = (MODE == 1) ? q.x : q.y;
                v[j] = __int_as_float(q.z);
            }
        }
        ushort4 s0 = *reinterpret_cast<const ushort4*>(src + (size_t)r[0] * 256 + lane * 4);
        ushort4 s1 = *reinterpret_cast<const ushort4*>(src + (size_t)r[1] * 256 + lane * 4);
        ushort4 s2 = *reinterpret_cast<const ushort4*>(src + (size_t)r[2] * 256 + lane * 4);
        ushort4 s3 = *reinterpret_cast<const ushort4*>(src + (size_t)r[3] * 256 + lane * 4);
        acc.x += v[0] * bf2f(s0.x); acc.y += v[0] * bf2f(s0.y);
        acc.z += v[0] * bf2f(s0.z); acc.w += v[0] * bf2f(s0.w);
        acc.x += v[1] * bf2f(s1.x); acc.y += v[1] * bf2f(s1.y);
        acc.z += v[1] * bf2f(s1.z); acc.w += v[1] * bf2f(s1.w);
        acc.x += v[2] * bf2f(s2.x); acc.y += v[2] * bf2f(s2.y);
        acc.z += v[2] * bf2f(s2.z); acc.w += v[2] * bf2f(s2.w);
        acc.x += v[3] * bf2f(s3.x); acc.y += v[3] * bf2f(s3.y);
        acc.z += v[3] * bf2f(s3.z); acc.w += v[3] * bf2f(s3.w);
    }
    for (; k < end; ++k) {
        int r; float v;
        if constexpr (MODE == 0) {
            int2 q = ((const int2*)listv)[k];
            r = q.x; v = __int_as_float(q.y);
        } else {
            int4 q = ((const int4*)listv)[k];
            r = (MODE == 1) ? q.x : q.y;
            v = __int_as_float(q.z);
        }
        ushort4 sv = *reinterpret_cast<const ushort4*>(src + (size_t)r * 256 + lane * 4);
        acc.x += v * bf2f(sv.x); acc.y += v * bf2f(sv.y);
        acc.z += v * bf2f(sv.z); acc.w += v * bf2f(sv.w);
    }
    return acc;
}
__device__ __forceinline__ void store_bf4(u16* dst, int seg, int lane, float4 o) {
    ushort4 o4;
    o4.x = f2bf(o.x); o4.y = f2bf(o.y); o4.z = f2bf(o.z); o4.w = f2bf(o.w);
    *reinterpret_cast<ushort4*>(dst + (size_t)seg * 256 + lane * 4) = o4;
}

// ---------------- 256-dim segment gather-sum kernel (standalone) --------------------
template <int MODE, bool EPI, bool ATT>
__global__ __launch_bounds__(256) void gather256_kernel(const int* __restrict__ rowptr,
                                                        const void* __restrict__ listv,
                                                        const u16* __restrict__ src,
                                                        const float* __restrict__ bias,
                                                        u16* __restrict__ dst, int nseg,
                                                        const float* __restrict__ attW,
                                                        const float* __restrict__ attb,
                                                        const float* __restrict__ tfidf,
                                                        float* __restrict__ e) {
    int seg = (blockIdx.x * 256 + threadIdx.x) >> 6;
    int lane = threadIdx.x & 63;
    if (seg >= nseg) return;
    float4 o = seg_gather<MODE>(rowptr, listv, src, seg, lane);
    if constexpr (EPI) {
        float4 bv = reinterpret_cast<const float4*>(bias)[lane];
        o.x = fmaxf(o.x + bv.x, 0.f); o.y = fmaxf(o.y + bv.y, 0.f);
        o.z = fmaxf(o.z + bv.z, 0.f); o.w = fmaxf(o.w + bv.w, 0.f);
    }
    store_bf4(dst, seg, lane, o);
    if constexpr (ATT) {
        float4 aw = reinterpret_cast<const float4*>(attW)[lane];
        float pe = o.x * aw.x + o.y * aw.y + o.z * aw.z + o.w * aw.w;
#pragma unroll
        for (int off = 32; off > 0; off >>= 1) pe += __shfl_down(pe, off);
        if (lane == 0)
            e[seg] = pe + tfidf[seg * 2] * attW[HID_] + tfidf[seg * 2 + 1] * attW[HID_ + 1]
                     + attb[0];
    }
}

// ---------------- MFMA GEMM, full-N tile 64x256: C = A @ Wt^T -----------------------
template <bool SPLIT_A, bool EPI, bool ATT>
__global__ __launch_bounds__(256) void gemm_mfma_kernel(const void* __restrict__ Av,
                                                        int M, int K, int Ks,
                                                        const u16* __restrict__ Bth,
                                                        const u16* __restrict__ Btl, int bstride,
                                                        const float* __restrict__ bias,
                                                        void* __restrict__ Cv,
                                                        const float* __restrict__ attWA,
                                                        float* __restrict__ EAp,
                                                        const float* __restrict__ attW,
                                                        const float* __restrict__ attb,
                                                        const float* __restrict__ tfidf,
                                                        float* __restrict__ e) {
    __shared__ __align__(16) u16 Ah[64 * 32];
    __shared__ __align__(16) u16 Al[64 * 32];
    __shared__ __align__(16) u16 Bh[256 * 32];
    __shared__ __align__(16) u16 Bl[256 * 32];
    int tid = threadIdx.x;
    int bm0 = blockIdx.x * 64;
    int w = tid >> 6, l = tid & 63;
    int srow = tid >> 2;
    int skbp = tid & 3;
    int skbl = skbp ^ ((srow >> 1) & 3);
    int arow = bm0 + srow; if (arow >= M) arow = M - 1;
    int sdst = srow * 32 + skbp * 8;
    int frow = w * 16 + (l & 15);
    int akbp = (l >> 4) ^ ((frow >> 1) & 3);

    f32x4 acc[16] = {};
    float ea = 0.f;
    int nkt = (K + 31) / 32;
    for (int kt = 0; kt < nkt; ++kt) {
        if (kt) __syncthreads();
        int kbase = kt * 32 + skbl * 8;
        if constexpr (SPLIT_A) {
            const float* Arow = (const float*)Av + (size_t)arow * Ks;
            float av[8];
            if (kbase + 8 <= K) {
                float4 v0 = *reinterpret_cast<const float4*>(Arow + kbase);
                float4 v1 = *reinterpret_cast<const float4*>(Arow + kbase + 4);
                av[0] = v0.x; av[1] = v0.y; av[2] = v0.z; av[3] = v0.w;
                av[4] = v1.x; av[5] = v1.y; av[6] = v1.z; av[7] = v1.w;
            } else {
#pragma unroll
                for (int ee = 0; ee < 8; ++ee) {
                    int kk = kbase + ee;
                    av[ee] = (kk < K) ? Arow[kk] : 0.f;
                }
            }
            if (EAp) {
#pragma unroll
                for (int ee = 0; ee < 8; ++ee) {
                    int kk = kbase + ee;
                    ea += av[ee] * ((kk < K) ? attWA[kk] : 0.f);
                }
            }
            short8 h8, l8;
#pragma unroll
            for (int ee = 0; ee < 8; ++ee) {
                u16 hi = f2bf(av[ee]);
                h8[ee] = (short)hi;
                l8[ee] = (short)f2bf(av[ee] - bf2f(hi));
            }
            *(short8*)&Ah[sdst] = h8;
            *(short8*)&Al[sdst] = l8;
        } else {
            const u16* Arow = (const u16*)Av + (size_t)arow * Ks;
            *(short8*)&Ah[sdst] = *(const short8*)(Arow + kbase);
        }
#pragma unroll
        for (int i = 0; i < 4; ++i) {
            int br = i * 64 + srow;
            int bkl = skbp ^ ((br >> 1) & 3);
            *(short8*)&Bh[br * 32 + skbp * 8] =
                *(const short8*)(Bth + (size_t)br * bstride + kt * 32 + bkl * 8);
            *(short8*)&Bl[br * 32 + skbp * 8] =
                *(const short8*)(Btl + (size_t)br * bstride + kt * 32 + bkl * 8);
        }
        __syncthreads();
        short8 ah = *(const short8*)&Ah[frow * 32 + akbp * 8];
        short8 al;
        if constexpr (SPLIT_A) al = *(const short8*)&Al[frow * 32 + akbp * 8];
#pragma unroll
        for (int nt = 0; nt < 16; ++nt) {
            int nrow = nt * 16 + (l & 15);
            int bkbp = (l >> 4) ^ ((nrow >> 1) & 3);
            short8 tbh = *(const short8*)&Bh[nrow * 32 + bkbp * 8];
            short8 tbl = *(const short8*)&Bl[nrow * 32 + bkbp * 8];
            acc[nt] = __builtin_amdgcn_mfma_f32_16x16x32_bf16(ah, tbh, acc[nt], 0, 0, 0);
            if constexpr (SPLIT_A)
                acc[nt] = __builtin_amdgcn_mfma_f32_16x16x32_bf16(al, tbh, acc[nt], 0, 0, 0);
            acc[nt] = __builtin_amdgcn_mfma_f32_16x16x32_bf16(ah, tbl, acc[nt], 0, 0, 0);
        }
    }
    if constexpr (SPLIT_A) {
        if (EAp) {
            ea += __shfl_xor(ea, 1);
            ea += __shfl_xor(ea, 2);
            if ((tid & 3) == 0 && bm0 + srow < M) EAp[bm0 + srow] = ea;
        }
    }
#pragma unroll
    for (int r = 0; r < 4; ++r) {
        int row = bm0 + w * 16 + (l >> 4) * 4 + r;
        if (row >= M) continue;
        float er = 0.f;
#pragma unroll
        for (int nt = 0; nt < 16; ++nt) {
            int col = nt * 16 + (l & 15);
            float v = acc[nt][r];
            if constexpr (EPI) {
                v = v + bias[col];
                v = v > 0.f ? v : 0.f;
            }
            if constexpr (ATT) er += v * attW[col];
            ((u16*)Cv)[(size_t)row * 256 + col] = f2bf(v);
        }
        if constexpr (ATT) {
            er += __shfl_xor(er, 1);
            er += __shfl_xor(er, 2);
            er += __shfl_xor(er, 4);
            er += __shfl_xor(er, 8);
            if ((l & 15) == 0)
                e[row] = er + tfidf[row * 2] * attW[HID_] + tfidf[row * 2 + 1] * attW[HID_ + 1]
                         + attb[0];
        }
    }
}

// ---------------- pool partial body (device fn, callable from fused kernels) --------
template <bool L0>
__device__ __forceinline__ void pool_body(int b, int c,
                                          const void* __restrict__ h, int dim, int stride,
                                          const int* __restrict__ x,
                                          const float* __restrict__ EA_or_e,
                                          const float* __restrict__ tfidf,
                                          const float* __restrict__ attWtail,
                                          const float* __restrict__ attb,
                                          float* __restrict__ psum,
                                          float* __restrict__ pmax) {
    int t = threadIdx.x;
    __shared__ float sev[N_];
    __shared__ int srows[N_];
    __shared__ float red[256];
    __shared__ float wv[PVN];
    int n0 = b * N_ + t, n1 = n0 + 256;
    float ev0, ev1;
    int r0, r1;
    if constexpr (L0) {
        r0 = x[n0]; r1 = x[n1];
        float a0 = attWtail[0], a1 = attWtail[1], ab = attb[0];
        ev0 = EA_or_e[r0] + tfidf[n0 * 2] * a0 + tfidf[n0 * 2 + 1] * a1 + ab;
        ev1 = EA_or_e[r1] + tfidf[n1 * 2] * a0 + tfidf[n1 * 2 + 1] * a1 + ab;
    } else {
        r0 = n0; r1 = n1;
        ev0 = EA_or_e[n0]; ev1 = EA_or_e[n1];
    }
    sev[t] = ev0; sev[t + 256] = ev1;
    srows[t] = r0; srows[t + 256] = r1;
    red[t] = fmaxf(ev0, ev1);
    __syncthreads();
    for (int s = 128; s > 0; s >>= 1) {
        if (t < s) red[t] = fmaxf(red[t], red[t + s]);
        __syncthreads();
    }
    float mx = red[0];
    __syncthreads();
    red[t] = expf(ev0 - mx) + expf(ev1 - mx);
    __syncthreads();
    for (int s = 128; s > 0; s >>= 1) {
        if (t < s) red[t] += red[t + s];
        __syncthreads();
    }
    float inv = 1.f / (red[0] + 1e-10f);
    if (t < PVN) wv[t] = expf(sev[c * PVN + t] - mx) * inv;
    __syncthreads();
    float s0 = 0.f, s1 = 0.f, m0 = -3.4e38f, m1 = -3.4e38f;
    int d0 = t, d1 = t + 256;
    bool has1 = d1 < dim;
    for (int i = 0; i < PVN; ++i) {
        int row = srows[c * PVN + i];
        float ww = wv[i];
        float x0, x1 = 0.f;
        if constexpr (L0) {
            const float* hp = (const float*)h + (size_t)row * stride;
            x0 = hp[d0];
            if (has1) x1 = hp[d1];
        } else {
            const u16* hp = (const u16*)h + (size_t)row * stride;
            x0 = bf2f(hp[d0]);
            if (has1) x1 = bf2f(hp[d1]);
        }
        s0 += ww * x0;
        m0 = fmaxf(m0, x0);
        if (has1) {
            s1 += ww * x1;
            m1 = fmaxf(m1, x1);
        }
    }
    size_t base = ((size_t)b * PCHUNK + c) * dim;
    psum[base + d0] = s0;
    pmax[base + d0] = m0;
    if (has1) {
        psum[base + d1] = s1;
        pmax[base + d1] = m1;
    }
}

// ---------------- standalone pool kernel (layer 2) ----------------------------------
template <bool L0>
__global__ __launch_bounds__(256) void pool_partial_kernel(const void* __restrict__ h, int dim,
                                                           int stride,
                                                           const int* __restrict__ x,
                                                           const float* __restrict__ EA_or_e,
                                                           const float* __restrict__ tfidf,
                                                           const float* __restrict__ attWtail,
                                                           const float* __restrict__ attb,
                                                           float* __restrict__ psum,
                                                           float* __restrict__ pmax) {
    pool_body<L0>(blockIdx.x, blockIdx.y, h, dim, stride, x, EA_or_e,
                  tfidf, attWtail, attb, psum, pmax);
}

// ---------------- fused: pool partial (blocks 0..511) || e-gather (rest) ------------
template <bool L0, int EMODE>
__global__ __launch_bounds__(256) void pool_gather_kernel(const void* __restrict__ h, int dim,
                                                          int stride,
                                                          const int* __restrict__ x,
                                                          const float* __restrict__ EA_or_e,
                                                          const float* __restrict__ tfidf,
                                                          const float* __restrict__ attWtail,
                                                          const float* __restrict__ attb,
                                                          float* __restrict__ psum,
                                                          float* __restrict__ pmax,
                                                          const int* __restrict__ rowptr,
                                                          const void* __restrict__ listv,
                                                          const u16* __restrict__ src,
                                                          u16* __restrict__ dst) {
    if (blockIdx.x < POOL_BLOCKS) {
        pool_body<L0>(blockIdx.x >> 3, blockIdx.x & 7, h, dim, stride, x, EA_or_e,
                      tfidf, attWtail, attb, psum, pmax);
    } else {
        int blk = blockIdx.x - POOL_BLOCKS;
        int seg = (blk * 256 + threadIdx.x) >> 6;
        int lane = threadIdx.x & 63;
        if (seg < NE_)
            store_bf4(dst, seg, lane, seg_gather<EMODE>(rowptr, listv, src, seg, lane));
    }
}

// ---------------- final: combine chunk partials on the fly + GEMV -------------------
__global__ __launch_bounds__(256) void final_kernel(const float* __restrict__ ps0,
                                                    const float* __restrict__ pm0,
                                                    const float* __restrict__ ps1,
                                                    const float* __restrict__ pm1,
                                                    const float* __restrict__ ps2,
                                                    const float* __restrict__ pm2,
                                                    const float* __restrict__ pW0,
                                                    const float* __restrict__ pb0,
                                                    const float* __restrict__ pW1,
                                                    const float* __restrict__ pb1,
                                                    const float* __restrict__ pW2,
                                                    const float* __restrict__ pb2,
                                                    float* __restrict__ out) {
    int b = blockIdx.x;
    int t = threadIdx.x;
    int lane = t & 63, wv = t >> 6;
    float acc[NC_] = {};
    for (int k = t; k < 2 * D_; k += 256) {
        float pv;
        if (k < D_) {
            pv = 0.f;
#pragma unroll
            for (int c = 0; c < PCHUNK; ++c) pv += ps0[((size_t)b * PCHUNK + c) * D_ + k];
        } else {
            pv = -3.4e38f;
#pragma unroll
            for (int c = 0; c < PCHUNK; ++c)
                pv = fmaxf(pv, pm0[((size_t)b * PCHUNK + c) * D_ + (k - D_)]);
        }
        const float* wp = pW0 + (size_t)k * NC_;
#pragma unroll
        for (int c = 0; c < NC_; ++c) acc[c] += pv * wp[c];
    }
    for (int k = t; k < 2 * HID_; k += 256) {
        float pv;
        if (k < HID_) {
            pv = 0.f;
#pragma unroll
            for (int c = 0; c < PCHUNK; ++c) pv += ps1[((size_t)b * PCHUNK + c) * HID_ + k];
        } else {
            pv = -3.4e38f;
#pragma unroll
            for (int c = 0; c < PCHUNK; ++c)
                pv = fmaxf(pv, pm1[((size_t)b * PCHUNK + c) * HID_ + (k - HID_)]);
        }
        const float* wp = pW1 + (size_t)k * NC_;
#pragma unroll
        for (int c = 0; c < NC_; ++c) acc[c] += pv * wp[c];
    }
    for (int k = t; k < 2 * HID_; k += 256) {
        float pv;
        if (k < HID_) {
            pv = 0.f;
#pragma unroll
            for (int c = 0; c < PCHUNK; ++c) pv += ps2[((size_t)b * PCHUNK + c) * HID_ + k];
        } else {
            pv = -3.4e38f;
#pragma unroll
            for (int c = 0; c < PCHUNK; ++c)
                pv = fmaxf(pv, pm2[((size_t)b * PCHUNK + c) * HID_ + (k - HID_)]);
        }
        const float* wp = pW2 + (size_t)k * NC_;
#pragma unroll
        for (int c = 0; c < NC_; ++c) acc[c] += pv * wp[c];
    }
    __shared__ float red[4][NC_];
#pragma unroll
    for (int c = 0; c < NC_; ++c) {
        float s = acc[c];
#pragma unroll
        for (int off = 32; off > 0; off >>= 1) s += __shfl_down(s, off);
        if (lane == 0) red[wv][c] = s;
    }
    __syncthreads();
    if (t < NC_) {
        float s = red[0][t] + red[1][t] + red[2][t] + red[3][t];
        out[b * NC_ + t] = s + pb0[t] + pb1[t] + pb2[t];
    }
}

extern "C" void kernel_launch(void* const* d_in, const int* in_sizes, int n_in,
                              void* d_out, int out_size, void* d_ws, size_t ws_size,
                              hipStream_t stream) {
    const int*   x         = (const int*)d_in[0];
    const int*   inc_rows  = (const int*)d_in[1];
    const int*   inc_cols  = (const int*)d_in[2];
    const float* inc_vals  = (const float*)d_in[3];
    const int*   sent_rows = (const int*)d_in[4];
    const int*   sent_cols = (const int*)d_in[5];
    const float* sent_vals = (const float*)d_in[6];
    const float* deg_v     = (const float*)d_in[7];
    const float* deg_e     = (const float*)d_in[8];
    const float* tf_idf = (const float*)d_in[11];
    const float* emb    = (const float*)d_in[12];
    const float* W1 = (const float*)d_in[13];
    const float* b1 = (const float*)d_in[14];
    const float* W2 = (const float*)d_in[15];
    const float* b2 = (const float*)d_in[16];
    const float* attW0 = (const float*)d_in[17];
    const float* attb0 = (const float*)d_in[18];
    const float* attW1 = (const float*)d_in[19];
    const float* attb1 = (const float*)d_in[20];
    const float* attW2 = (const float*)d_in[21];
    const float* attb2 = (const float*)d_in[22];
    const float* pW0 = (const float*)d_in[23];
    const float* pb0 = (const float*)d_in[24];
    const float* pW1 = (const float*)d_in[25];
    const float* pb1 = (const float*)d_in[26];
    const float* pW2 = (const float*)d_in[27];
    const float* pb2 = (const float*)d_in[28];
    float* out = (float*)d_out;

    // workspace layout
    char* ws = (char*)d_ws;
    size_t off = 0;
    auto alloc = [&](size_t bytes) {
        void* p = ws + off;
        off += (bytes + 255) & ~(size_t)255;
        return p;
    };
    u16* EW = (u16*)alloc((size_t)VOCAB_ * HID_ * sizeof(u16)); // emb @ W1, bf16
    u16* MW = (u16*)alloc((size_t)NE_ * HID_ * sizeof(u16));    // m2 @ W2, bf16
    u16* m  = (u16*)alloc((size_t)NE_ * HID_ * sizeof(u16));
    u16* m2 = (u16*)alloc((size_t)NE_ * HID_ * sizeof(u16));
    u16* h1 = (u16*)alloc((size_t)NV_ * HID_ * sizeof(u16));
    u16* h2 = (u16*)alloc((size_t)NV_ * HID_ * sizeof(u16));
    u16* Wt1h = (u16*)alloc((size_t)HID_ * 320 * sizeof(u16));
    u16* Wt1l = (u16*)alloc((size_t)HID_ * 320 * sizeof(u16));
    u16* Wt2h = (u16*)alloc((size_t)HID_ * 256 * sizeof(u16));
    u16* Wt2l = (u16*)alloc((size_t)HID_ * 256 * sizeof(u16));
    float* EA = (float*)alloc((size_t)VOCAB_ * sizeof(float));  // emb @ attW0[:300]
    float* e  = (float*)alloc((size_t)NV_ * sizeof(float));
    float* ps0 = (float*)alloc((size_t)B_ * PCHUNK * D_ * sizeof(float));
    float* pm0 = (float*)alloc((size_t)B_ * PCHUNK * D_ * sizeof(float));
    float* ps1 = (float*)alloc((size_t)B_ * PCHUNK * HID_ * sizeof(float));
    float* pm1 = (float*)alloc((size_t)B_ * PCHUNK * HID_ * sizeof(float));
    float* ps2 = (float*)alloc((size_t)B_ * PCHUNK * HID_ * sizeof(float));
    float* pm2 = (float*)alloc((size_t)B_ * PCHUNK * HID_ * sizeof(float));
    // CSR structures
    int* cnt  = (int*)alloc((size_t)SCAN_TOT * sizeof(int));  // [cnt_e|cnt_v|cnt_s]
    int* fill = (int*)alloc((size_t)SCAN_TOT * sizeof(int));
    int* rowptr_e = (int*)alloc((size_t)(NE_ + 1) * sizeof(int));
    int* rowptr_v = (int*)alloc((size_t)(NV_ + 1) * sizeof(int));
    int* rowptr_s = (int*)alloc((size_t)(NE_ + 1) * sizeof(int));
    int* bsum  = (int*)alloc((size_t)SCAN_NCH * sizeof(int));
    int4* elist = (int4*)alloc((size_t)NNZ_ * sizeof(int4));
    int2* vlist = (int2*)alloc((size_t)NNZ_ * sizeof(int2));
    int2* slist = (int2*)alloc((size_t)SNNZ_ * sizeof(int2));

    // ---- build CSR (hist+wconv fused; scanB folded into scanC; packed place) ----
    hipMemsetAsync(cnt, 0, (size_t)SCAN_TOT * sizeof(int), stream);
    hist_wconv_kernel<<<NNZ_ / 256, 256, 0, stream>>>(inc_rows, inc_cols, sent_cols, cnt,
                                                      W1, W2, Wt1h, Wt1l, Wt2h, Wt2l);
    scanA_kernel<<<SCAN_NCH, 256, 0, stream>>>(cnt, bsum);
    scanC_kernel<<<SCAN_NCH, 256, 0, stream>>>(cnt, bsum, rowptr_e, rowptr_v, rowptr_s, fill);
    place_kernel<<<NNZ_ / 256, 256, 0, stream>>>(inc_rows, inc_cols, inc_vals,
                                                 sent_rows, sent_cols, sent_vals,
                                                 x, deg_e, deg_v, fill,
                                                 elist, vlist, slist);

    // ---- EW = emb @ W1 (bf16 out) + EA = emb @ attW0 (free, f32) ----
    gemm_mfma_kernel<true, false, false><<<(VOCAB_ + 63) / 64, 256, 0, stream>>>(
        emb, VOCAB_, D_, D_, Wt1h, Wt1l, 320, nullptr, EW,
        attW0, EA, nullptr, nullptr, nullptr, nullptr);

    // ---- fused: pool layer 0 (logits from EA) || layer-1 e-gather ----
    pool_gather_kernel<true, 2><<<POOL_BLOCKS + EGATHER_BLOCKS, 256, 0, stream>>>(
        emb, D_, D_, x, EA, tf_idf, attW0 + D_, attb0, ps0, pm0,
        rowptr_e, elist, EW, m);

    // ---- layer 1: s-gather, v-gather (EPI+ATT) ----
    gather256_kernel<0, false, false><<<NE_ / 4, 256, 0, stream>>>(
        rowptr_s, slist, m, nullptr, m2, NE_, nullptr, nullptr, nullptr, nullptr);
    gather256_kernel<0, true, true><<<NV_ / 4, 256, 0, stream>>>(
        rowptr_v, vlist, m2, b1, h1, NV_, attW1, attb1, tf_idf, e);

    // ---- fused: pool layer 1 || layer-2 e-gather ----
    pool_gather_kernel<false, 1><<<POOL_BLOCKS + EGATHER_BLOCKS, 256, 0, stream>>>(
        h1, HID_, HID_, nullptr, e, nullptr, nullptr, nullptr, ps1, pm1,
        rowptr_e, elist, h1, m);

    // ---- layer 2: s-gather, W2 hoisted to edge level, v-gather ----
    gather256_kernel<0, false, false><<<NE_ / 4, 256, 0, stream>>>(
        rowptr_s, slist, m, nullptr, m2, NE_, nullptr, nullptr, nullptr, nullptr);
    gemm_mfma_kernel<false, false, false><<<NE_ / 64, 256, 0, stream>>>(
        m2, NE_, HID_, HID_, Wt2h, Wt2l, 256, nullptr, MW,
        nullptr, nullptr, nullptr, nullptr, nullptr, nullptr);
    gather256_kernel<0, true, true><<<NV_ / 4, 256, 0, stream>>>(
        rowptr_v, vlist, MW, b2, h2, NV_, attW2, attb2, tf_idf, e);

    // ---- pool layer 2 ----
    {
        dim3 pg(B_, PCHUNK);
        pool_partial_kernel<false><<<pg, 256, 0, stream>>>(h2, HID_, HID_, nullptr, e,
                                                           nullptr, nullptr, nullptr,
                                                           ps2, pm2);
    }

    // ---- final (fused combine + GEMV) ----
    final_kernel<<<B_, 256, 0, stream>>>(ps0, pm0, ps1, pm1, ps2, pm2,
                                         pW0, pb0, pW1, pb1, pW2, pb2, out);
}

// Round 18
// 252.728 us; speedup vs baseline: 6.3888x; 1.0058x over previous
//
#include <hip/hip_runtime.h>
#include <cstddef>

#define B_   64
#define N_   512
#define NV_  32768
#define NE_  8192
#define NNZ_ 262144
#define SNNZ_ 24576
#define D_   300
#define HID_ 256
#define NC_  10
#define VOCAB_ 30000
#define PCHUNK 8
#define PVN (N_ / PCHUNK)   // 64 nodes per pool chunk
#define POOL_BLOCKS (B_ * PCHUNK)       // 512
#define EGATHER_BLOCKS (NE_ / 4)        // 2048

#define SCAN_TOT (NE_ + NV_ + NE_)      // 49152 counts, contiguous [cnt_e|cnt_v|cnt_s]
#define SCAN_NCH (SCAN_TOT / 1024)      // 48 chunks
#define SEG1_CH  (NE_ / 1024)           // 8  (start of cnt_v chunks)
#define SEG2_CH  ((NE_ + NV_) / 1024)   // 40 (start of cnt_s chunks)
#define WCONV_TOT (256 * 320 + 256 * 256)

using u16 = unsigned short;
typedef __attribute__((ext_vector_type(8))) short short8;
typedef __attribute__((ext_vector_type(4))) float f32x4;

__device__ __forceinline__ float bf2f(u16 v) {
    union { unsigned int u; float f; } uf;
    uf.u = ((unsigned int)v) << 16;
    return uf.f;
}
__device__ __forceinline__ u16 f2bf(float f) {
    union { float f; unsigned int u; } uf; uf.f = f;
    unsigned int u = uf.u;
    unsigned int r = u + 0x7fffu + ((u >> 16) & 1u);
    return (u16)(r >> 16);
}

// ---------------- CSR build + weight conversion -------------------------------------
__global__ __launch_bounds__(256) void hist_wconv_kernel(const int* __restrict__ inc_rows,
                                                         const int* __restrict__ inc_cols,
                                                         const int* __restrict__ sent_cols,
                                                         int* __restrict__ cnt,
                                                         const float* __restrict__ W1,
                                                         const float* __restrict__ W2,
                                                         u16* __restrict__ Wt1h,
                                                         u16* __restrict__ Wt1l,
                                                         u16* __restrict__ Wt2h,
                                                         u16* __restrict__ Wt2l) {
    int i = blockIdx.x * 256 + threadIdx.x;
    atomicAdd(&cnt[inc_cols[i]], 1);
    atomicAdd(&cnt[NE_ + inc_rows[i]], 1);
    if (i < SNNZ_) atomicAdd(&cnt[NE_ + NV_ + sent_cols[i]], 1);
    if (i < WCONV_TOT) {
        int id = i;
        const float* W; u16 *Wh, *Wl; int K, KP;
        if (id < 256 * 320) { W = W1; Wh = Wt1h; Wl = Wt1l; K = D_; KP = 320; }
        else { id -= 256 * 320; W = W2; Wh = Wt2h; Wl = Wt2l; K = HID_; KP = 256; }
        int n = id & 255, k = id >> 8;
        float v = (k < K) ? W[(size_t)k * HID_ + n] : 0.f;
        u16 hi = f2bf(v);
        Wh[(size_t)n * KP + k] = hi;
        Wl[(size_t)n * KP + k] = f2bf(v - bf2f(hi));
    }
}

__global__ __launch_bounds__(256) void scanA_kernel(const int* __restrict__ cnt,
                                                    int* __restrict__ bsum) {
    int blk = blockIdx.x, t = threadIdx.x;
    int4 v = reinterpret_cast<const int4*>(cnt)[blk * 256 + t];
    int s = v.x + v.y + v.z + v.w;
    __shared__ int red[256];
    red[t] = s;
    __syncthreads();
    for (int o = 128; o > 0; o >>= 1) {
        if (t < o) red[t] += red[t + o];
        __syncthreads();
    }
    if (t == 0) bsum[blk] = red[0];
}

__global__ __launch_bounds__(256) void scanC_kernel(const int* __restrict__ cnt,
                                                    const int* __restrict__ bsum,
                                                    int* __restrict__ rowptr_e,
                                                    int* __restrict__ rowptr_v,
                                                    int* __restrict__ rowptr_s,
                                                    int* __restrict__ fill) {
    int blk = blockIdx.x, t = threadIdx.x;
    int segstart = (blk < SEG1_CH) ? 0 : ((blk < SEG2_CH) ? SEG1_CH : SEG2_CH);
    int cbase = 0;
    for (int c = segstart; c < blk; ++c) cbase += bsum[c];
    int gi = blk * 1024 + t * 4;
    int4 v = reinterpret_cast<const int4*>(cnt)[blk * 256 + t];
    int s0 = v.x, s1 = s0 + v.y, s2 = s1 + v.z, s3 = s2 + v.w;
    __shared__ int part[256];
    part[t] = s3;
    __syncthreads();
    for (int o = 1; o < 256; o <<= 1) {
        int a = (t >= o) ? part[t - o] : 0;
        __syncthreads();
        part[t] += a;
        __syncthreads();
    }
    int excl = (t > 0 ? part[t - 1] : 0) + cbase;
    int4 e;
    e.x = excl; e.y = excl + s0; e.z = excl + s1; e.w = excl + s2;
    int* rp; int li;
    if (blk < SEG1_CH)      { rp = rowptr_e; li = gi; }
    else if (blk < SEG2_CH) { rp = rowptr_v; li = gi - NE_; }
    else                    { rp = rowptr_s; li = gi - NE_ - NV_; }
    rp[li + 0] = e.x; rp[li + 1] = e.y; rp[li + 2] = e.z; rp[li + 3] = e.w;
    reinterpret_cast<int4*>(fill)[blk * 256 + t] = e;
    if (t == 255) {
        int tot = excl + s3;
        if (blk == SEG1_CH - 1) rowptr_e[NE_] = tot;
        if (blk == SEG2_CH - 1) rowptr_v[NV_] = tot;
        if (blk == SCAN_NCH - 1) rowptr_s[NE_] = tot;
    }
}

__global__ __launch_bounds__(256) void place_kernel(const int* __restrict__ inc_rows,
                                                    const int* __restrict__ inc_cols,
                                                    const float* __restrict__ inc_vals,
                                                    const int* __restrict__ sent_rows,
                                                    const int* __restrict__ sent_cols,
                                                    const float* __restrict__ sent_vals,
                                                    const int* __restrict__ x,
                                                    const float* __restrict__ deg_e,
                                                    const float* __restrict__ deg_v,
                                                    int* __restrict__ fill,
                                                    int4* __restrict__ elist,
                                                    int2* __restrict__ vlist,
                                                    int2* __restrict__ slist) {
    int i = blockIdx.x * 256 + threadIdx.x;
    int r = inc_rows[i], c = inc_cols[i];
    float v = inc_vals[i];
    int pe = atomicAdd(&fill[c], 1);
    int4 ee;
    ee.x = r; ee.y = x[r];
    ee.z = __float_as_int(v * deg_e[c]); ee.w = 0;
    elist[pe] = ee;
    int pv = atomicAdd(&fill[NE_ + r], 1);
    int2 vv;
    vv.x = c; vv.y = __float_as_int(v * deg_v[r]);
    vlist[pv] = vv;
    if (i < SNNZ_) {
        int ps = atomicAdd(&fill[NE_ + NV_ + sent_cols[i]], 1);
        int2 ss;
        ss.x = sent_rows[i]; ss.y = __float_as_int(sent_vals[i]);
        slist[ps] = ss;
    }
}

// ---------------- per-wave 256-dim gather helpers (8/4-way pipelined) ---------------
template <int MODE>
__device__ __forceinline__ void list_entry(const void* __restrict__ listv, int k,
                                           int& r, float& v) {
    if constexpr (MODE == 0) {
        int2 q = ((const int2*)listv)[k];
        r = q.x; v = __int_as_float(q.y);
    } else {
        int4 q = ((const int4*)listv)[k];
        r = (MODE == 1) ? q.x : q.y;
        v = __int_as_float(q.z);
    }
}

template <int MODE>
__device__ __forceinline__ float4 seg_gather(const int* __restrict__ rowptr,
                                             const void* __restrict__ listv,
                                             const u16* __restrict__ src,
                                             int seg, int lane) {
    int start = rowptr[seg], end = rowptr[seg + 1];
    float4 acc = make_float4(0.f, 0.f, 0.f, 0.f);
    int k = start;
    // 8-way batched: 8 independent row loads in flight per wave
    for (; k + 8 <= end; k += 8) {
        int r[8]; float v[8];
#pragma unroll
        for (int j = 0; j < 8; ++j) list_entry<MODE>(listv, k + j, r[j], v[j]);
        ushort4 s[8];
#pragma unroll
        for (int j = 0; j < 8; ++j)
            s[j] = *reinterpret_cast<const ushort4*>(src + (size_t)r[j] * 256 + lane * 4);
#pragma unroll
        for (int j = 0; j < 8; ++j) {
            acc.x += v[j] * bf2f(s[j].x); acc.y += v[j] * bf2f(s[j].y);
            acc.z += v[j] * bf2f(s[j].z); acc.w += v[j] * bf2f(s[j].w);
        }
    }
    // 4-way mid tier
    for (; k + 4 <= end; k += 4) {
        int r[4]; float v[4];
#pragma unroll
        for (int j = 0; j < 4; ++j) list_entry<MODE>(listv, k + j, r[j], v[j]);
        ushort4 s[4];
#pragma unroll
        for (int j = 0; j < 4; ++j)
            s[j] = *reinterpret_cast<const ushort4*>(src + (size_t)r[j] * 256 + lane * 4);
#pragma unroll
        for (int j = 0; j < 4; ++j) {
            acc.x += v[j] * bf2f(s[j].x); acc.y += v[j] * bf2f(s[j].y);
            acc.z += v[j] * bf2f(s[j].z); acc.w += v[j] * bf2f(s[j].w);
        }
    }
    for (; k < end; ++k) {
        int r; float v;
        list_entry<MODE>(listv, k, r, v);
        ushort4 sv = *reinterpret_cast<const ushort4*>(src + (size_t)r * 256 + lane * 4);
        acc.x += v * bf2f(sv.x); acc.y += v * bf2f(sv.y);
        acc.z += v * bf2f(sv.z); acc.w += v * bf2f(sv.w);
    }
    return acc;
}
__device__ __forceinline__ void store_bf4(u16* dst, int seg, int lane, float4 o) {
    ushort4 o4;
    o4.x = f2bf(o.x); o4.y = f2bf(o.y); o4.z = f2bf(o.z); o4.w = f2bf(o.w);
    *reinterpret_cast<ushort4*>(dst + (size_t)seg * 256 + lane * 4) = o4;
}

// ---------------- 256-dim segment gather-sum kernel (standalone) --------------------
template <int MODE, bool EPI, bool ATT>
__global__ __launch_bounds__(256) void gather256_kernel(const int* __restrict__ rowptr,
                                                        const void* __restrict__ listv,
                                                        const u16* __restrict__ src,
                                                        const float* __restrict__ bias,
                                                        u16* __restrict__ dst, int nseg,
                                                        const float* __restrict__ attW,
                                                        const float* __restrict__ attb,
                                                        const float* __restrict__ tfidf,
                                                        float* __restrict__ e) {
    int seg = (blockIdx.x * 256 + threadIdx.x) >> 6;
    int lane = threadIdx.x & 63;
    if (seg >= nseg) return;
    float4 o = seg_gather<MODE>(rowptr, listv, src, seg, lane);
    if constexpr (EPI) {
        float4 bv = reinterpret_cast<const float4*>(bias)[lane];
        o.x = fmaxf(o.x + bv.x, 0.f); o.y = fmaxf(o.y + bv.y, 0.f);
        o.z = fmaxf(o.z + bv.z, 0.f); o.w = fmaxf(o.w + bv.w, 0.f);
    }
    store_bf4(dst, seg, lane, o);
    if constexpr (ATT) {
        float4 aw = reinterpret_cast<const float4*>(attW)[lane];
        float pe = o.x * aw.x + o.y * aw.y + o.z * aw.z + o.w * aw.w;
#pragma unroll
        for (int off = 32; off > 0; off >>= 1) pe += __shfl_down(pe, off);
        if (lane == 0)
            e[seg] = pe + tfidf[seg * 2] * attW[HID_] + tfidf[seg * 2 + 1] * attW[HID_ + 1]
                     + attb[0];
    }
}

// ---------------- MFMA GEMM, full-N tile 64x256: C = A @ Wt^T -----------------------
template <bool SPLIT_A, bool EPI, bool ATT>
__global__ __launch_bounds__(256) void gemm_mfma_kernel(const void* __restrict__ Av,
                                                        int M, int K, int Ks,
                                                        const u16* __restrict__ Bth,
                                                        const u16* __restrict__ Btl, int bstride,
                                                        const float* __restrict__ bias,
                                                        void* __restrict__ Cv,
                                                        const float* __restrict__ attWA,
                                                        float* __restrict__ EAp,
                                                        const float* __restrict__ attW,
                                                        const float* __restrict__ attb,
                                                        const float* __restrict__ tfidf,
                                                        float* __restrict__ e) {
    __shared__ __align__(16) u16 Ah[64 * 32];
    __shared__ __align__(16) u16 Al[64 * 32];
    __shared__ __align__(16) u16 Bh[256 * 32];
    __shared__ __align__(16) u16 Bl[256 * 32];
    int tid = threadIdx.x;
    int bm0 = blockIdx.x * 64;
    int w = tid >> 6, l = tid & 63;
    int srow = tid >> 2;
    int skbp = tid & 3;
    int skbl = skbp ^ ((srow >> 1) & 3);
    int arow = bm0 + srow; if (arow >= M) arow = M - 1;
    int sdst = srow * 32 + skbp * 8;
    int frow = w * 16 + (l & 15);
    int akbp = (l >> 4) ^ ((frow >> 1) & 3);

    f32x4 acc[16] = {};
    float ea = 0.f;
    int nkt = (K + 31) / 32;
    for (int kt = 0; kt < nkt; ++kt) {
        if (kt) __syncthreads();
        int kbase = kt * 32 + skbl * 8;
        if constexpr (SPLIT_A) {
            const float* Arow = (const float*)Av + (size_t)arow * Ks;
            float av[8];
            if (kbase + 8 <= K) {
                float4 v0 = *reinterpret_cast<const float4*>(Arow + kbase);
                float4 v1 = *reinterpret_cast<const float4*>(Arow + kbase + 4);
                av[0] = v0.x; av[1] = v0.y; av[2] = v0.z; av[3] = v0.w;
                av[4] = v1.x; av[5] = v1.y; av[6] = v1.z; av[7] = v1.w;
            } else {
#pragma unroll
                for (int ee = 0; ee < 8; ++ee) {
                    int kk = kbase + ee;
                    av[ee] = (kk < K) ? Arow[kk] : 0.f;
                }
            }
            if (EAp) {
#pragma unroll
                for (int ee = 0; ee < 8; ++ee) {
                    int kk = kbase + ee;
                    ea += av[ee] * ((kk < K) ? attWA[kk] : 0.f);
                }
            }
            short8 h8, l8;
#pragma unroll
            for (int ee = 0; ee < 8; ++ee) {
                u16 hi = f2bf(av[ee]);
                h8[ee] = (short)hi;
                l8[ee] = (short)f2bf(av[ee] - bf2f(hi));
            }
            *(short8*)&Ah[sdst] = h8;
            *(short8*)&Al[sdst] = l8;
        } else {
            const u16* Arow = (const u16*)Av + (size_t)arow * Ks;
            *(short8*)&Ah[sdst] = *(const short8*)(Arow + kbase);
        }
#pragma unroll
        for (int i = 0; i < 4; ++i) {
            int br = i * 64 + srow;
            int bkl = skbp ^ ((br >> 1) & 3);
            *(short8*)&Bh[br * 32 + skbp * 8] =
                *(const short8*)(Bth + (size_t)br * bstride + kt * 32 + bkl * 8);
            *(short8*)&Bl[br * 32 + skbp * 8] =
                *(const short8*)(Btl + (size_t)br * bstride + kt * 32 + bkl * 8);
        }
        __syncthreads();
        short8 ah = *(const short8*)&Ah[frow * 32 + akbp * 8];
        short8 al;
        if constexpr (SPLIT_A) al = *(const short8*)&Al[frow * 32 + akbp * 8];
#pragma unroll
        for (int nt = 0; nt < 16; ++nt) {
            int nrow = nt * 16 + (l & 15);
            int bkbp = (l >> 4) ^ ((nrow >> 1) & 3);
            short8 tbh = *(const short8*)&Bh[nrow * 32 + bkbp * 8];
            short8 tbl = *(const short8*)&Bl[nrow * 32 + bkbp * 8];
            acc[nt] = __builtin_amdgcn_mfma_f32_16x16x32_bf16(ah, tbh, acc[nt], 0, 0, 0);
            if constexpr (SPLIT_A)
                acc[nt] = __builtin_amdgcn_mfma_f32_16x16x32_bf16(al, tbh, acc[nt], 0, 0, 0);
            acc[nt] = __builtin_amdgcn_mfma_f32_16x16x32_bf16(ah, tbl, acc[nt], 0, 0, 0);
        }
    }
    if constexpr (SPLIT_A) {
        if (EAp) {
            ea += __shfl_xor(ea, 1);
            ea += __shfl_xor(ea, 2);
            if ((tid & 3) == 0 && bm0 + srow < M) EAp[bm0 + srow] = ea;
        }
    }
#pragma unroll
    for (int r = 0; r < 4; ++r) {
        int row = bm0 + w * 16 + (l >> 4) * 4 + r;
        if (row >= M) continue;
        float er = 0.f;
#pragma unroll
        for (int nt = 0; nt < 16; ++nt) {
            int col = nt * 16 + (l & 15);
            float v = acc[nt][r];
            if constexpr (EPI) {
                v = v + bias[col];
                v = v > 0.f ? v : 0.f;
            }
            if constexpr (ATT) er += v * attW[col];
            ((u16*)Cv)[(size_t)row * 256 + col] = f2bf(v);
        }
        if constexpr (ATT) {
            er += __shfl_xor(er, 1);
            er += __shfl_xor(er, 2);
            er += __shfl_xor(er, 4);
            er += __shfl_xor(er, 8);
            if ((l & 15) == 0)
                e[row] = er + tfidf[row * 2] * attW[HID_] + tfidf[row * 2 + 1] * attW[HID_ + 1]
                         + attb[0];
        }
    }
}

// ---------------- pool partial body (device fn, callable from fused kernels) --------
template <bool L0>
__device__ __forceinline__ void pool_body(int b, int c,
                                          const void* __restrict__ h, int dim, int stride,
                                          const int* __restrict__ x,
                                          const float* __restrict__ EA_or_e,
                                          const float* __restrict__ tfidf,
                                          const float* __restrict__ attWtail,
                                          const float* __restrict__ attb,
                                          float* __restrict__ psum,
                                          float* __restrict__ pmax) {
    int t = threadIdx.x;
    __shared__ float sev[N_];
    __shared__ int srows[N_];
    __shared__ float red[256];
    __shared__ float wv[PVN];
    int n0 = b * N_ + t, n1 = n0 + 256;
    float ev0, ev1;
    int r0, r1;
    if constexpr (L0) {
        r0 = x[n0]; r1 = x[n1];
        float a0 = attWtail[0], a1 = attWtail[1], ab = attb[0];
        ev0 = EA_or_e[r0] + tfidf[n0 * 2] * a0 + tfidf[n0 * 2 + 1] * a1 + ab;
        ev1 = EA_or_e[r1] + tfidf[n1 * 2] * a0 + tfidf[n1 * 2 + 1] * a1 + ab;
    } else {
        r0 = n0; r1 = n1;
        ev0 = EA_or_e[n0]; ev1 = EA_or_e[n1];
    }
    sev[t] = ev0; sev[t + 256] = ev1;
    srows[t] = r0; srows[t + 256] = r1;
    red[t] = fmaxf(ev0, ev1);
    __syncthreads();
    for (int s = 128; s > 0; s >>= 1) {
        if (t < s) red[t] = fmaxf(red[t], red[t + s]);
        __syncthreads();
    }
    float mx = red[0];
    __syncthreads();
    red[t] = expf(ev0 - mx) + expf(ev1 - mx);
    __syncthreads();
    for (int s = 128; s > 0; s >>= 1) {
        if (t < s) red[t] += red[t + s];
        __syncthreads();
    }
    float inv = 1.f / (red[0] + 1e-10f);
    if (t < PVN) wv[t] = expf(sev[c * PVN + t] - mx) * inv;
    __syncthreads();
    float s0 = 0.f, s1 = 0.f, m0 = -3.4e38f, m1 = -3.4e38f;
    int d0 = t, d1 = t + 256;
    bool has1 = d1 < dim;
    for (int i = 0; i < PVN; ++i) {
        int row = srows[c * PVN + i];
        float ww = wv[i];
        float x0, x1 = 0.f;
        if constexpr (L0) {
            const float* hp = (const float*)h + (size_t)row * stride;
            x0 = hp[d0];
            if (has1) x1 = hp[d1];
        } else {
            const u16* hp = (const u16*)h + (size_t)row * stride;
            x0 = bf2f(hp[d0]);
            if (has1) x1 = bf2f(hp[d1]);
        }
        s0 += ww * x0;
        m0 = fmaxf(m0, x0);
        if (has1) {
            s1 += ww * x1;
            m1 = fmaxf(m1, x1);
        }
    }
    size_t base = ((size_t)b * PCHUNK + c) * dim;
    psum[base + d0] = s0;
    pmax[base + d0] = m0;
    if (has1) {
        psum[base + d1] = s1;
        pmax[base + d1] = m1;
    }
}

// ---------------- standalone pool kernel (layer 2) ----------------------------------
template <bool L0>
__global__ __launch_bounds__(256) void pool_partial_kernel(const void* __restrict__ h, int dim,
                                                           int stride,
                                                           const int* __restrict__ x,
                                                           const float* __restrict__ EA_or_e,
                                                           const float* __restrict__ tfidf,
                                                           const float* __restrict__ attWtail,
                                                           const float* __restrict__ attb,
                                                           float* __restrict__ psum,
                                                           float* __restrict__ pmax) {
    pool_body<L0>(blockIdx.x, blockIdx.y, h, dim, stride, x, EA_or_e,
                  tfidf, attWtail, attb, psum, pmax);
}

// ---------------- fused: pool partial (blocks 0..511) || e-gather (rest) ------------
template <bool L0, int EMODE>
__global__ __launch_bounds__(256) void pool_gather_kernel(const void* __restrict__ h, int dim,
                                                          int stride,
                                                          const int* __restrict__ x,
                                                          const float* __restrict__ EA_or_e,
                                                          const float* __restrict__ tfidf,
                                                          const float* __restrict__ attWtail,
                                                          const float* __restrict__ attb,
                                                          float* __restrict__ psum,
                                                          float* __restrict__ pmax,
                                                          const int* __restrict__ rowptr,
                                                          const void* __restrict__ listv,
                                                          const u16* __restrict__ src,
                                                          u16* __restrict__ dst) {
    if (blockIdx.x < POOL_BLOCKS) {
        pool_body<L0>(blockIdx.x >> 3, blockIdx.x & 7, h, dim, stride, x, EA_or_e,
                      tfidf, attWtail, attb, psum, pmax);
    } else {
        int blk = blockIdx.x - POOL_BLOCKS;
        int seg = (blk * 256 + threadIdx.x) >> 6;
        int lane = threadIdx.x & 63;
        if (seg < NE_)
            store_bf4(dst, seg, lane, seg_gather<EMODE>(rowptr, listv, src, seg, lane));
    }
}

// ---------------- final: combine chunk partials on the fly + GEMV -------------------
__global__ __launch_bounds__(256) void final_kernel(const float* __restrict__ ps0,
                                                    const float* __restrict__ pm0,
                                                    const float* __restrict__ ps1,
                                                    const float* __restrict__ pm1,
                                                    const float* __restrict__ ps2,
                                                    const float* __restrict__ pm2,
                                                    const float* __restrict__ pW0,
                                                    const float* __restrict__ pb0,
                                                    const float* __restrict__ pW1,
                                                    const float* __restrict__ pb1,
                                                    const float* __restrict__ pW2,
                                                    const float* __restrict__ pb2,
                                                    float* __restrict__ out) {
    int b = blockIdx.x;
    int t = threadIdx.x;
    int lane = t & 63, wv = t >> 6;
    float acc[NC_] = {};
    for (int k = t; k < 2 * D_; k += 256) {
        float pv;
        if (k < D_) {
            pv = 0.f;
#pragma unroll
            for (int c = 0; c < PCHUNK; ++c) pv += ps0[((size_t)b * PCHUNK + c) * D_ + k];
        } else {
            pv = -3.4e38f;
#pragma unroll
            for (int c = 0; c < PCHUNK; ++c)
                pv = fmaxf(pv, pm0[((size_t)b * PCHUNK + c) * D_ + (k - D_)]);
        }
        const float* wp = pW0 + (size_t)k * NC_;
#pragma unroll
        for (int c = 0; c < NC_; ++c) acc[c] += pv * wp[c];
    }
    for (int k = t; k < 2 * HID_; k += 256) {
        float pv;
        if (k < HID_) {
            pv = 0.f;
#pragma unroll
            for (int c = 0; c < PCHUNK; ++c) pv += ps1[((size_t)b * PCHUNK + c) * HID_ + k];
        } else {
            pv = -3.4e38f;
#pragma unroll
            for (int c = 0; c < PCHUNK; ++c)
                pv = fmaxf(pv, pm1[((size_t)b * PCHUNK + c) * HID_ + (k - HID_)]);
        }
        const float* wp = pW1 + (size_t)k * NC_;
#pragma unroll
        for (int c = 0; c < NC_; ++c) acc[c] += pv * wp[c];
    }
    for (int k = t; k < 2 * HID_; k += 256) {
        float pv;
        if (k < HID_) {
            pv = 0.f;
#pragma unroll
            for (int c = 0; c < PCHUNK; ++c) pv += ps2[((size_t)b * PCHUNK + c) * HID_ + k];
        } else {
            pv = -3.4e38f;
#pragma unroll
            for (int c = 0; c < PCHUNK; ++c)
                pv = fmaxf(pv, pm2[((size_t)b * PCHUNK + c) * HID_ + (k - HID_)]);
        }
        const float* wp = pW2 + (size_t)k * NC_;
#pragma unroll
        for (int c = 0; c < NC_; ++c) acc[c] += pv * wp[c];
    }
    __shared__ float red[4][NC_];
#pragma unroll
    for (int c = 0; c < NC_; ++c) {
        float s = acc[c];
#pragma unroll
        for (int off = 32; off > 0; off >>= 1) s += __shfl_down(s, off);
        if (lane == 0) red[wv][c] = s;
    }
    __syncthreads();
    if (t < NC_) {
        float s = red[0][t] + red[1][t] + red[2][t] + red[3][t];
        out[b * NC_ + t] = s + pb0[t] + pb1[t] + pb2[t];
    }
}

extern "C" void kernel_launch(void* const* d_in, const int* in_sizes, int n_in,
                              void* d_out, int out_size, void* d_ws, size_t ws_size,
                              hipStream_t stream) {
    const int*   x         = (const int*)d_in[0];
    const int*   inc_rows  = (const int*)d_in[1];
    const int*   inc_cols  = (const int*)d_in[2];
    const float* inc_vals  = (const float*)d_in[3];
    const int*   sent_rows = (const int*)d_in[4];
    const int*   sent_cols = (const int*)d_in[5];
    const float* sent_vals = (const float*)d_in[6];
    const float* deg_v     = (const float*)d_in[7];
    const float* deg_e     = (const float*)d_in[8];
    const float* tf_idf = (const float*)d_in[11];
    const float* emb    = (const float*)d_in[12];
    const float* W1 = (const float*)d_in[13];
    const float* b1 = (const float*)d_in[14];
    const float* W2 = (const float*)d_in[15];
    const float* b2 = (const float*)d_in[16];
    const float* attW0 = (const float*)d_in[17];
    const float* attb0 = (const float*)d_in[18];
    const float* attW1 = (const float*)d_in[19];
    const float* attb1 = (const float*)d_in[20];
    const float* attW2 = (const float*)d_in[21];
    const float* attb2 = (const float*)d_in[22];
    const float* pW0 = (const float*)d_in[23];
    const float* pb0 = (const float*)d_in[24];
    const float* pW1 = (const float*)d_in[25];
    const float* pb1 = (const float*)d_in[26];
    const float* pW2 = (const float*)d_in[27];
    const float* pb2 = (const float*)d_in[28];
    float* out = (float*)d_out;

    // workspace layout
    char* ws = (char*)d_ws;
    size_t off = 0;
    auto alloc = [&](size_t bytes) {
        void* p = ws + off;
        off += (bytes + 255) & ~(size_t)255;
        return p;
    };
    u16* EW = (u16*)alloc((size_t)VOCAB_ * HID_ * sizeof(u16)); // emb @ W1, bf16
    u16* MW = (u16*)alloc((size_t)NE_ * HID_ * sizeof(u16));    // m2 @ W2, bf16
    u16* m  = (u16*)alloc((size_t)NE_ * HID_ * sizeof(u16));
    u16* m2 = (u16*)alloc((size_t)NE_ * HID_ * sizeof(u16));
    u16* h1 = (u16*)alloc((size_t)NV_ * HID_ * sizeof(u16));
    u16* h2 = (u16*)alloc((size_t)NV_ * HID_ * sizeof(u16));
    u16* Wt1h = (u16*)alloc((size_t)HID_ * 320 * sizeof(u16));
    u16* Wt1l = (u16*)alloc((size_t)HID_ * 320 * sizeof(u16));
    u16* Wt2h = (u16*)alloc((size_t)HID_ * 256 * sizeof(u16));
    u16* Wt2l = (u16*)alloc((size_t)HID_ * 256 * sizeof(u16));
    float* EA = (float*)alloc((size_t)VOCAB_ * sizeof(float));  // emb @ attW0[:300]
    float* e  = (float*)alloc((size_t)NV_ * sizeof(float));
    float* ps0 = (float*)alloc((size_t)B_ * PCHUNK * D_ * sizeof(float));
    float* pm0 = (float*)alloc((size_t)B_ * PCHUNK * D_ * sizeof(float));
    float* ps1 = (float*)alloc((size_t)B_ * PCHUNK * HID_ * sizeof(float));
    float* pm1 = (float*)alloc((size_t)B_ * PCHUNK * HID_ * sizeof(float));
    float* ps2 = (float*)alloc((size_t)B_ * PCHUNK * HID_ * sizeof(float));
    float* pm2 = (float*)alloc((size_t)B_ * PCHUNK * HID_ * sizeof(float));
    // CSR structures
    int* cnt  = (int*)alloc((size_t)SCAN_TOT * sizeof(int));  // [cnt_e|cnt_v|cnt_s]
    int* fill = (int*)alloc((size_t)SCAN_TOT * sizeof(int));
    int* rowptr_e = (int*)alloc((size_t)(NE_ + 1) * sizeof(int));
    int* rowptr_v = (int*)alloc((size_t)(NV_ + 1) * sizeof(int));
    int* rowptr_s = (int*)alloc((size_t)(NE_ + 1) * sizeof(int));
    int* bsum  = (int*)alloc((size_t)SCAN_NCH * sizeof(int));
    int4* elist = (int4*)alloc((size_t)NNZ_ * sizeof(int4));
    int2* vlist = (int2*)alloc((size_t)NNZ_ * sizeof(int2));
    int2* slist = (int2*)alloc((size_t)SNNZ_ * sizeof(int2));

    // ---- build CSR (hist+wconv fused; scanB folded into scanC; packed place) ----
    hipMemsetAsync(cnt, 0, (size_t)SCAN_TOT * sizeof(int), stream);
    hist_wconv_kernel<<<NNZ_ / 256, 256, 0, stream>>>(inc_rows, inc_cols, sent_cols, cnt,
                                                      W1, W2, Wt1h, Wt1l, Wt2h, Wt2l);
    scanA_kernel<<<SCAN_NCH, 256, 0, stream>>>(cnt, bsum);
    scanC_kernel<<<SCAN_NCH, 256, 0, stream>>>(cnt, bsum, rowptr_e, rowptr_v, rowptr_s, fill);
    place_kernel<<<NNZ_ / 256, 256, 0, stream>>>(inc_rows, inc_cols, inc_vals,
                                                 sent_rows, sent_cols, sent_vals,
                                                 x, deg_e, deg_v, fill,
                                                 elist, vlist, slist);

    // ---- EW = emb @ W1 (bf16 out) + EA = emb @ attW0 (free, f32) ----
    gemm_mfma_kernel<true, false, false><<<(VOCAB_ + 63) / 64, 256, 0, stream>>>(
        emb, VOCAB_, D_, D_, Wt1h, Wt1l, 320, nullptr, EW,
        attW0, EA, nullptr, nullptr, nullptr, nullptr);

    // ---- fused: pool layer 0 (logits from EA) || layer-1 e-gather ----
    pool_gather_kernel<true, 2><<<POOL_BLOCKS + EGATHER_BLOCKS, 256, 0, stream>>>(
        emb, D_, D_, x, EA, tf_idf, attW0 + D_, attb0, ps0, pm0,
        rowptr_e, elist, EW, m);

    // ---- layer 1: s-gather, v-gather (EPI+ATT) ----
    gather256_kernel<0, false, false><<<NE_ / 4, 256, 0, stream>>>(
        rowptr_s, slist, m, nullptr, m2, NE_, nullptr, nullptr, nullptr, nullptr);
    gather256_kernel<0, true, true><<<NV_ / 4, 256, 0, stream>>>(
        rowptr_v, vlist, m2, b1, h1, NV_, attW1, attb1, tf_idf, e);

    // ---- fused: pool layer 1 || layer-2 e-gather ----
    pool_gather_kernel<false, 1><<<POOL_BLOCKS + EGATHER_BLOCKS, 256, 0, stream>>>(
        h1, HID_, HID_, nullptr, e, nullptr, nullptr, nullptr, ps1, pm1,
        rowptr_e, elist, h1, m);

    // ---- layer 2: s-gather, W2 hoisted to edge level, v-gather ----
    gather256_kernel<0, false, false><<<NE_ / 4, 256, 0, stream>>>(
        rowptr_s, slist, m, nullptr, m2, NE_, nullptr, nullptr, nullptr, nullptr);
    gemm_mfma_kernel<false, false, false><<<NE_ / 64, 256, 0, stream>>>(
        m2, NE_, HID_, HID_, Wt2h, Wt2l, 256, nullptr, MW,
        nullptr, nullptr, nullptr, nullptr, nullptr, nullptr);
    gather256_kernel<0, true, true><<<NV_ / 4, 256, 0, stream>>>(
        rowptr_v, vlist, MW, b2, h2, NV_, attW2, attb2, tf_idf, e);

    // ---- pool layer 2 ----
    {
        dim3 pg(B_, PCHUNK);
        pool_partial_kernel<false><<<pg, 256, 0, stream>>>(h2, HID_, HID_, nullptr, e,
                                                           nullptr, nullptr, nullptr,
                                                           ps2, pm2);
    }

    // ---- final (fused combine + GEMV) ----
    final_kernel<<<B_, 256, 0, stream>>>(ps0, pm0, ps1, pm1, ps2, pm2,
                                         pW0, pb0, pW1, pb1, pW2, pb2, out);
}